// Round 9
// baseline (563.700 us; speedup 1.0000x reference)
//
#include <hip/hip_runtime.h>
#include <math.h>

namespace {

constexpr int NB = 4, NSPK = 2, NCHN = 6;
constexpr int LSIG = 64000;
constexpr int NFFT = 512, HOPSZ = 128, NFREQ = 257;
constexpr int NT = 505;               // frames
constexpr int TAPS = 20;
constexpr int NG = NB * NFREQ * NSPK; // 2056 systems
constexpr int NSIG = NB * NSPK * NCHN; // 48 istft signals
constexpr float PI_F = 3.14159265358979323846f;
constexpr double LAMBDA_REG = 2e-4;
constexpr float FCP_EPS_F = 1e-3f;
constexpr int G_ELEMS = NG * TAPS * NCHN; // 246720 floats (real part only)
constexpr int TSTRIP = 20;
constexpr int NSTRIP = (NT + TSTRIP - 1) / TSTRIP; // 26
constexpr int HALF_SC = NSIG / 2;     // 24 signals per half-pass

constexpr size_t WS_ALIGN = 256;
constexpr size_t align_up(size_t x) { return (x + WS_ALIGN - 1) & ~(WS_ALIGN - 1); }

// ws byte offsets
constexpr size_t SPH_B  = 0;                                        // [8][257][505] float2
constexpr size_t SPH_SZ = (size_t)NB * NSPK * NFREQ * NT * 8;
constexpr size_t SPHT_B = align_up(SPH_B + SPH_SZ);                 // [8][505][257] float2
constexpr size_t MXS_B  = align_up(SPHT_B + SPH_SZ);                // [24][257][505] float2
constexpr size_t MXS_SZ = (size_t)NB * NCHN * NFREQ * NT * 8;
constexpr size_t POW_B  = align_up(MXS_B + MXS_SZ);                 // [4][257][505] float
constexpr size_t POW_SZ = (size_t)NB * NFREQ * NT * 4;
constexpr size_t MX_B   = align_up(POW_B + POW_SZ);                 // [4] float
constexpr size_t R_B    = align_up(MX_B + (size_t)NB * 4);          // [2056][400] float2
constexpr size_t R_SZ   = (size_t)NG * TAPS * TAPS * 8;
constexpr size_t P_B    = align_up(R_B + R_SZ);                     // [2056][120] float2
constexpr size_t P_SZ   = (size_t)NG * TAPS * NCHN * 8;
constexpr size_t GCT_B  = align_up(P_B + P_SZ);                     // [8][20][6][257] float2
constexpr size_t GCT_SZ = (size_t)NB * NSPK * TAPS * NCHN * NFREQ * 8;
constexpr size_t FRM_B  = align_up(GCT_B + GCT_SZ);                 // [48][505][512] float
// spec[24][505][257] float2 aliases the mxs region (mxs dead after solve;
// same byte size: 24*257*505*8 == 24*505*257*8).
constexpr size_t SPEC_B = MXS_B;

__device__ __forceinline__ int rev9(int n) { return (int)(__brev((unsigned)n) >> 23); }

// In-LDS radix-2 DIT FFT, 512 points, 256 threads, input pre-bit-reversed.
// sign = -1 forward, +1 inverse (unscaled). HW-validated (r1 vs r2 bit-identical).
__device__ __forceinline__ void fft512(float2* buf, int tid, float sign) {
#pragma unroll
  for (int s = 1; s <= 9; ++s) {
    int half = 1 << (s - 1);
    int blk = tid >> (s - 1);
    int pos = tid & (half - 1);
    int i0 = (blk << s) + pos;
    int i1 = i0 + half;
    float ang = sign * 2.0f * PI_F * (float)pos / (float)(half << 1);
    float sn, cs;
    __sincosf(ang, &sn, &cs);
    float2 u = buf[i0];
    float2 v = buf[i1];
    float2 vw = make_float2(v.x * cs - v.y * sn, v.x * sn + v.y * cs);
    buf[i0] = make_float2(u.x + vw.x, u.y + vw.y);
    buf[i1] = make_float2(u.x - vw.x, u.y - vw.y);
    __syncthreads();
  }
}

// ---------------- STFT (radix-2 FFT) ----------------
__global__ void stft_kernel(const float* __restrict__ ref, const float* __restrict__ mix,
                            float2* __restrict__ sph, float2* __restrict__ spht,
                            float2* __restrict__ mxs) {
  __shared__ float2 buf[NFFT];
  int blk = blockIdx.x;
  int sig = blk / NT;
  int t = blk - sig * NT;
  int tid = threadIdx.x;
  bool is_ref = sig < NB * NSPK;
  int m = is_ref ? sig : (sig - NB * NSPK);
  const float* src = is_ref ? (ref + (size_t)m * LSIG) : (mix + (size_t)m * LSIG);

  for (int n = tid; n < NFFT; n += 256) {
    int g = t * HOPSZ + n - NFFT / 2;
    float v = (g >= 0 && g < LSIG) ? src[g] : 0.0f;
    float w = __sinf(PI_F * (float)n / (float)NFFT);  // sqrt-hann
    buf[rev9(n)] = make_float2(v * w, 0.0f);
  }
  __syncthreads();
  fft512(buf, tid, -1.0f);

  if (is_ref) {
    float2* d1 = sph + (size_t)m * NFREQ * NT;
    float2* d2 = spht + ((size_t)m * NT + t) * NFREQ;
    for (int f = tid; f < NFREQ; f += 256) {
      float2 v = buf[f];
      d1[(size_t)f * NT + t] = v;
      d2[f] = v;
    }
  } else {
    float2* d1 = mxs + (size_t)m * NFREQ * NT;
    for (int f = tid; f < NFREQ; f += 256) d1[(size_t)f * NT + t] = buf[f];
  }
}

// ---------------- power ----------------
__global__ void power_kernel(const float2* __restrict__ mxs, float* __restrict__ power) {
  int i = blockIdx.x * 256 + threadIdx.x;
  if (i >= NB * NFREQ * NT) return;
  int b = i / (NFREQ * NT);
  int r = i - b * (NFREQ * NT);
  float acc = 0.0f;
#pragma unroll
  for (int c = 0; c < NCHN; ++c) {
    float2 v = mxs[(size_t)(b * NCHN + c) * NFREQ * NT + r];
    acc += v.x * v.x + v.y * v.y;
  }
  power[i] = acc * (1.0f / (float)NCHN);
}

// ---------------- per-batch max ----------------
__global__ void max_kernel(const float* __restrict__ power, float* __restrict__ mx) {
  int b = blockIdx.x;
  const float* p = power + (size_t)b * NFREQ * NT;
  float m = 0.0f;
  for (int i = threadIdx.x; i < NFREQ * NT; i += 256) m = fmaxf(m, p[i]);
#pragma unroll
  for (int off = 32; off > 0; off >>= 1) m = fmaxf(m, __shfl_down(m, off, 64));
  __shared__ float sm[4];
  int wave = threadIdx.x >> 6, lane = threadIdx.x & 63;
  if (lane == 0) sm[wave] = m;
  __syncthreads();
  if (threadIdx.x == 0) mx[b] = fmaxf(fmaxf(sm[0], sm[1]), fmaxf(sm[2], sm[3]));
}

// ---------------- R / P accumulation (fp32, Hermitian R) ----------------
__global__ void rp_kernel(const float2* __restrict__ sph, const float2* __restrict__ mxs,
                          const float* __restrict__ power, const float* __restrict__ mx,
                          float2* __restrict__ R, float2* __restrict__ P) {
  __shared__ float2 Ysh[NT];
  __shared__ float2 MWsh[NCHN][NT];   // w[t] * conj(M[c][t])
  __shared__ float Wsh[NT];
  int g = blockIdx.x;
  int s = g & 1;
  int bf = g >> 1;
  int f = bf % NFREQ;
  int b = bf / NFREQ;
  int tid = threadIdx.x;

  const float2* yrow = sph + ((size_t)(b * NSPK + s) * NFREQ + f) * NT;
  const float* prow = power + ((size_t)b * NFREQ + f) * NT;
  float add = mx[b] * FCP_EPS_F + 1e-6f;
  for (int t = tid; t < NT; t += 384) {
    Wsh[t] = 1.0f / (prow[t] + add);
    Ysh[t] = yrow[t];
  }
  __syncthreads();
  for (int i = tid; i < NCHN * NT; i += 384) {
    int c = i / NT, t = i - c * NT;
    float2 m = mxs[((size_t)(b * NCHN + c) * NFREQ + f) * NT + t];
    float w = Wsh[t];
    MWsh[c][t] = make_float2(w * m.x, -w * m.y);
  }
  __syncthreads();

  const float invT = 1.0f / (float)NT;
  if (tid < TAPS * (TAPS + 1) / 2) {
    int p = (int)((sqrtf(8.0f * (float)tid + 1.0f) - 1.0f) * 0.5f);
    while ((p + 1) * (p + 2) / 2 <= tid) ++p;
    while (p * (p + 1) / 2 > tid) --p;
    int q = tid - p * (p + 1) / 2;
    int t0 = (TAPS - 1) - q;
    float ax = 0.0f, ay = 0.0f;
    for (int t = t0; t < NT; ++t) {
      float w = Wsh[t];
      float2 a = Ysh[t - (TAPS - 1) + p];
      float2 bb = Ysh[t - (TAPS - 1) + q];
      float rr = a.x * bb.x + a.y * bb.y;
      float ii = a.y * bb.x - a.x * bb.y;
      ax = fmaf(w, rr, ax);
      ay = fmaf(w, ii, ay);
    }
    ax *= invT; ay *= invT;
    R[(size_t)g * TAPS * TAPS + p * TAPS + q] = make_float2(ax, ay);
    R[(size_t)g * TAPS * TAPS + q * TAPS + p] = make_float2(ax, -ay);
  } else if (tid >= 256 && tid < 256 + TAPS * NCHN) {
    int i = tid - 256;
    int p = i / NCHN, c = i - p * NCHN;
    int t0 = (TAPS - 1) - p;
    float ax = 0.0f, ay = 0.0f;
    for (int t = t0; t < NT; ++t) {
      float2 a = Ysh[t - (TAPS - 1) + p];
      float2 mw = MWsh[c][t];
      ax += a.x * mw.x - a.y * mw.y;
      ay += a.x * mw.y + a.y * mw.x;
    }
    P[(size_t)g * TAPS * NCHN + i] = make_float2(ax * invT, ay * invT);
  }
}

// ---------------- LU solve with partial pivoting (complex128) ----------------
__global__ void solve_kernel(const float2* __restrict__ R, const float2* __restrict__ P,
                             float* __restrict__ gout, float2* __restrict__ gct) {
  __shared__ double2 A[TAPS][TAPS];
  __shared__ double2 Bm[TAPS][NCHN];
  __shared__ int piv;
  int g = blockIdx.x;
  int tid = threadIdx.x;
  int s = g & 1;
  int bf = g >> 1;
  int f = bf % NFREQ;
  int b = bf / NFREQ;
  int bs = b * NSPK + s;

  for (int i = tid; i < TAPS * TAPS; i += 64) {
    float2 r = R[(size_t)g * TAPS * TAPS + i];
    A[i / TAPS][i % TAPS] = make_double2((double)r.x, (double)r.y);
  }
  for (int i = tid; i < TAPS * NCHN; i += 64) {
    float2 p = P[(size_t)g * TAPS * NCHN + i];
    Bm[i / NCHN][i % NCHN] = make_double2((double)p.x, (double)p.y);
  }
  __syncthreads();
  if (tid < TAPS) A[tid][tid].x += LAMBDA_REG;
  __syncthreads();

  for (int k = 0; k < TAPS; ++k) {
    if (tid == 0) {
      int r = k;
      double best = fabs(A[k][k].x) + fabs(A[k][k].y);
      for (int i = k + 1; i < TAPS; ++i) {
        double v = fabs(A[i][k].x) + fabs(A[i][k].y);
        if (v > best) { best = v; r = i; }
      }
      piv = r;
    }
    __syncthreads();
    int r = piv;
    if (r != k) {
      if (tid < TAPS) {
        double2 tmp = A[k][tid]; A[k][tid] = A[r][tid]; A[r][tid] = tmp;
      } else if (tid < TAPS + NCHN) {
        int c = tid - TAPS;
        double2 tmp = Bm[k][c]; Bm[k][c] = Bm[r][c]; Bm[r][c] = tmp;
      }
    }
    __syncthreads();
    double2 akk = A[k][k];
    double den = akk.x * akk.x + akk.y * akk.y;
    if (tid > k && tid < TAPS) {
      double2 a = A[tid][k];
      A[tid][k] = make_double2((a.x * akk.x + a.y * akk.y) / den,
                               (a.y * akk.x - a.x * akk.y) / den);
    }
    __syncthreads();
    int nr = TAPS - 1 - k;
    int nc = nr + NCHN;
    for (int idx = tid; idx < nr * nc; idx += 64) {
      int i = k + 1 + idx / nc;
      int jj = idx % nc;
      double2 mlt = A[i][k];
      if (jj < nr) {
        int j = k + 1 + jj;
        double2 u = A[k][j];
        A[i][j].x -= mlt.x * u.x - mlt.y * u.y;
        A[i][j].y -= mlt.x * u.y + mlt.y * u.x;
      } else {
        int c = jj - nr;
        double2 u = Bm[k][c];
        Bm[i][c].x -= mlt.x * u.x - mlt.y * u.y;
        Bm[i][c].y -= mlt.x * u.y + mlt.y * u.x;
      }
    }
    __syncthreads();
  }

  if (tid < NCHN) {
    int c = tid;
    for (int k = TAPS - 1; k >= 0; --k) {
      double sx = Bm[k][c].x, sy = Bm[k][c].y;
      for (int j = k + 1; j < TAPS; ++j) {
        double2 u = A[k][j], xv = Bm[j][c];
        sx -= u.x * xv.x - u.y * xv.y;
        sy -= u.x * xv.y + u.y * xv.x;
      }
      double2 akk = A[k][k];
      double den = akk.x * akk.x + akk.y * akk.y;
      Bm[k][c] = make_double2((sx * akk.x + sy * akk.y) / den,
                              (sy * akk.x - sx * akk.y) / den);
    }
  }
  __syncthreads();

  for (int i = tid; i < TAPS * NCHN; i += 64) {
    int p = i / NCHN, c = i - p * NCHN;
    double2 gv = Bm[p][c];
    float gx = (float)gv.x, gy = (float)(-gv.y);  // conj(G)
    gout[(size_t)g * TAPS * NCHN + i] = gx;       // float32, real part only
    gct[(((size_t)bs * TAPS + p) * NCHN + c) * NFREQ + f] = make_float2(gx, gy);
  }
}

// ---------------- ret as register-blocked sliding convolution ----------------
// spec[scl][t][f] = sum_p spht[bs][t-19+p][f] * gct[bs][p][c][f]
// One thread: (scl, strip of 20 t, f). G and acc in registers; 39 streamed Y loads.
__global__ void conv_kernel(const float2* __restrict__ spht, const float2* __restrict__ gct,
                            float2* __restrict__ spec, int sc0) {
  int gid = blockIdx.x * 256 + threadIdx.x;
  constexpr int TOTAL = HALF_SC * NSTRIP * NFREQ;
  if (gid >= TOTAL) return;
  int f = gid % NFREQ;
  int rest = gid / NFREQ;
  int strip = rest % NSTRIP;
  int scl = rest / NSTRIP;
  int sc = sc0 + scl;
  int c = sc % NCHN, bs = sc / NCHN;
  int t0 = strip * TSTRIP;

  float2 g[TAPS];
#pragma unroll
  for (int p = 0; p < TAPS; ++p)
    g[p] = gct[(((size_t)bs * TAPS + p) * NCHN + c) * NFREQ + f];

  float2 acc[TSTRIP];
#pragma unroll
  for (int i = 0; i < TSTRIP; ++i) acc[i] = make_float2(0.0f, 0.0f);

  const float2* yb = spht + (size_t)bs * NT * NFREQ + f;
#pragma unroll
  for (int k = 0; k < TSTRIP + TAPS - 1; ++k) {  // 39 streamed inputs
    int u = t0 - (TAPS - 1) + k;
    float2 y = (u >= 0 && u < NT) ? yb[(size_t)u * NFREQ] : make_float2(0.0f, 0.0f);
#pragma unroll
    for (int i = 0; i < TSTRIP; ++i) {
      constexpr int dummy = 0; (void)dummy;
      int p = k - i;
      if (p >= 0 && p < TAPS) {  // compile-time pruned after unroll
        acc[i].x += y.x * g[p].x - y.y * g[p].y;
        acc[i].y += y.x * g[p].y + y.y * g[p].x;
      }
    }
  }
  float2* sp = spec + ((size_t)scl * NT + t0) * NFREQ + f;
#pragma unroll
  for (int i = 0; i < TSTRIP; ++i)
    if (t0 + i < NT) sp[(size_t)i * NFREQ] = acc[i];
}

// ---------------- inverse FFT + window (radix-2) ----------------
// grid: HALF_SC*NT blocks. Reads spec coalesced, Hermitian scatter, fft, write.
__global__ void ifft_kernel(const float2* __restrict__ spec, float* __restrict__ frames,
                            int sc0) {
  __shared__ float2 buf[NFFT];
  int blk = blockIdx.x;
  int t = blk % NT;
  int scl = blk / NT;
  int sc = sc0 + scl;
  int tid = threadIdx.x;

  const float2* sp = spec + ((size_t)scl * NT + t) * NFREQ;
  for (int f = tid; f < NFREQ; f += 256) {
    float2 v = sp[f];
    buf[rev9(f)] = v;
    if (f > 0 && f < NFFT / 2) buf[rev9(NFFT - f)] = make_float2(v.x, -v.y);
  }
  __syncthreads();
  fft512(buf, tid, +1.0f);

  float* frow = frames + ((size_t)sc * NT + t) * NFFT;
  for (int n = tid; n < NFFT; n += 256) {
    float w = __sinf(PI_F * (float)n / (float)NFFT);
    frow[n] = buf[n].x * (1.0f / (float)NFFT) * w;
  }
}

// ---------------- overlap-add + env normalize + crop (float32 out) ----------------
// Interior samples: 4 overlapping sin^2 windows sum to exactly 2.
__global__ void ola_kernel(const float* __restrict__ frames, float* __restrict__ out) {
  int i = blockIdx.x * 256 + threadIdx.x;
  if (i >= NSIG * LSIG) return;
  int sig = i / LSIG;
  int l = i - sig * LSIG;
  int lp = l + NFFT / 2;
  int j0 = max(0, (lp - (NFFT - HOPSZ)) / HOPSZ);
  int j1 = min(NT - 1, lp / HOPSZ);
  float acc = 0.0f;
  for (int j = j0; j <= j1; ++j) {
    int n = lp - j * HOPSZ;
    acc += frames[((size_t)sig * NT + j) * NFFT + n];
  }
  float env;
  if (j1 - j0 == 3) {
    env = 2.0f;  // sum sin^2(theta + k*pi/4), k=0..3 == 2 exactly
  } else {
    env = 0.0f;
    for (int j = j0; j <= j1; ++j) {
      int n = lp - j * HOPSZ;
      float w = __sinf(PI_F * (float)n / (float)NFFT);
      env += w * w;
    }
    if (env <= 1e-11f) env = 1.0f;
  }
  out[(size_t)G_ELEMS + i] = acc / env;
}

}  // namespace

extern "C" void kernel_launch(void* const* d_in, const int* in_sizes, int n_in,
                              void* d_out, int out_size, void* d_ws, size_t ws_size,
                              hipStream_t stream) {
  const float* ref = (const float*)d_in[0];
  const float* mix = (const float*)d_in[1];
  if (n_in >= 2 && in_sizes[0] > in_sizes[1]) {
    const float* tmp = ref; ref = mix; mix = tmp;
  }
  char* ws = (char*)d_ws;

  float2*  sph   = (float2*)(ws + SPH_B);
  float2*  spht  = (float2*)(ws + SPHT_B);
  float2*  mxs   = (float2*)(ws + MXS_B);
  float*   power = (float*)(ws + POW_B);
  float*   mx    = (float*)(ws + MX_B);
  float2*  R     = (float2*)(ws + R_B);
  float2*  P     = (float2*)(ws + P_B);
  float2*  gct   = (float2*)(ws + GCT_B);
  float*   frames= (float*)(ws + FRM_B);
  float2*  spec  = (float2*)(ws + SPEC_B);  // aliases mxs (dead after solve)
  float*   out   = (float*)d_out;

  stft_kernel<<<dim3((NB * NSPK + NB * NCHN) * NT), dim3(256), 0, stream>>>(ref, mix, sph, spht, mxs);
  power_kernel<<<dim3((NB * NFREQ * NT + 255) / 256), dim3(256), 0, stream>>>(mxs, power);
  max_kernel<<<dim3(NB), dim3(256), 0, stream>>>(power, mx);
  rp_kernel<<<dim3(NG), dim3(384), 0, stream>>>(sph, mxs, power, mx, R, P);
  solve_kernel<<<dim3(NG), dim3(64), 0, stream>>>(R, P, out, gct);

  constexpr int CONV_THREADS = HALF_SC * NSTRIP * NFREQ;
  for (int half = 0; half < 2; ++half) {
    int sc0 = half * HALF_SC;
    conv_kernel<<<dim3((CONV_THREADS + 255) / 256), dim3(256), 0, stream>>>(spht, gct, spec, sc0);
    ifft_kernel<<<dim3(HALF_SC * NT), dim3(256), 0, stream>>>(spec, frames, sc0);
  }
  ola_kernel<<<dim3((NSIG * LSIG + 255) / 256), dim3(256), 0, stream>>>(frames, out);
}

// Round 10
// 502.458 us; speedup vs baseline: 1.1219x; 1.1219x over previous
//
#include <hip/hip_runtime.h>
#include <math.h>

namespace {

constexpr int NB = 4, NSPK = 2, NCHN = 6;
constexpr int LSIG = 64000;
constexpr int NFFT = 512, HOPSZ = 128, NFREQ = 257;
constexpr int NT = 505;               // frames
constexpr int TAPS = 20;
constexpr int NG = NB * NFREQ * NSPK; // 2056 systems
constexpr int NSIG = NB * NSPK * NCHN; // 48 istft signals
constexpr float PI_F = 3.14159265358979323846f;
constexpr double LAMBDA_REG = 2e-4;
constexpr float FCP_EPS_F = 1e-3f;
constexpr int G_ELEMS = NG * TAPS * NCHN; // 246720 floats (real part only)

constexpr size_t WS_ALIGN = 256;
constexpr size_t align_up(size_t x) { return (x + WS_ALIGN - 1) & ~(WS_ALIGN - 1); }

// ws byte offsets
constexpr size_t SPH_B  = 0;                                        // [8][257][505] float2
constexpr size_t SPH_SZ = (size_t)NB * NSPK * NFREQ * NT * 8;
constexpr size_t SPHT_B = align_up(SPH_B + SPH_SZ);                 // [8][505][257] float2
constexpr size_t MXS_B  = align_up(SPHT_B + SPH_SZ);                // [24][257][505] float2
constexpr size_t MXS_SZ = (size_t)NB * NCHN * NFREQ * NT * 8;
constexpr size_t POW_B  = align_up(MXS_B + MXS_SZ);                 // [4][257][505] float
constexpr size_t POW_SZ = (size_t)NB * NFREQ * NT * 4;
constexpr size_t MX_B   = align_up(POW_B + POW_SZ);                 // [4] float
constexpr size_t R_B    = align_up(MX_B + (size_t)NB * 4);          // [2056][400] float2
constexpr size_t R_SZ   = (size_t)NG * TAPS * TAPS * 8;
constexpr size_t P_B    = align_up(R_B + R_SZ);                     // [2056][120] float2
constexpr size_t P_SZ   = (size_t)NG * TAPS * NCHN * 8;
constexpr size_t GCT_B  = align_up(P_B + P_SZ);                     // [8][20][6][257] float2
constexpr size_t GCT_SZ = (size_t)NB * NSPK * TAPS * NCHN * NFREQ * 8;
constexpr size_t FRM_B  = align_up(GCT_B + GCT_SZ);                 // [48][505][512] float

__device__ __forceinline__ int rev9(int n) { return (int)(__brev((unsigned)n) >> 23); }

// In-LDS radix-2 DIT FFT, 512 points, 256 threads, input pre-bit-reversed.
// sign = -1 forward, +1 inverse (unscaled). HW-validated (r1 vs r2 bit-identical).
__device__ __forceinline__ void fft512(float2* buf, int tid, float sign) {
#pragma unroll
  for (int s = 1; s <= 9; ++s) {
    int half = 1 << (s - 1);
    int blk = tid >> (s - 1);
    int pos = tid & (half - 1);
    int i0 = (blk << s) + pos;
    int i1 = i0 + half;
    float ang = sign * 2.0f * PI_F * (float)pos / (float)(half << 1);
    float sn, cs;
    __sincosf(ang, &sn, &cs);
    float2 u = buf[i0];
    float2 v = buf[i1];
    float2 vw = make_float2(v.x * cs - v.y * sn, v.x * sn + v.y * cs);
    buf[i0] = make_float2(u.x + vw.x, u.y + vw.y);
    buf[i1] = make_float2(u.x - vw.x, u.y - vw.y);
    __syncthreads();
  }
}

// ---------------- STFT (radix-2 FFT) ----------------
__global__ void stft_kernel(const float* __restrict__ ref, const float* __restrict__ mix,
                            float2* __restrict__ sph, float2* __restrict__ spht,
                            float2* __restrict__ mxs) {
  __shared__ float2 buf[NFFT];
  int blk = blockIdx.x;
  int sig = blk / NT;
  int t = blk - sig * NT;
  int tid = threadIdx.x;
  bool is_ref = sig < NB * NSPK;
  int m = is_ref ? sig : (sig - NB * NSPK);
  const float* src = is_ref ? (ref + (size_t)m * LSIG) : (mix + (size_t)m * LSIG);

  for (int n = tid; n < NFFT; n += 256) {
    int g = t * HOPSZ + n - NFFT / 2;
    float v = (g >= 0 && g < LSIG) ? src[g] : 0.0f;
    float w = __sinf(PI_F * (float)n / (float)NFFT);  // sqrt-hann
    buf[rev9(n)] = make_float2(v * w, 0.0f);
  }
  __syncthreads();
  fft512(buf, tid, -1.0f);

  if (is_ref) {
    float2* d1 = sph + (size_t)m * NFREQ * NT;
    float2* d2 = spht + ((size_t)m * NT + t) * NFREQ;
    for (int f = tid; f < NFREQ; f += 256) {
      float2 v = buf[f];
      d1[(size_t)f * NT + t] = v;
      d2[f] = v;
    }
  } else {
    float2* d1 = mxs + (size_t)m * NFREQ * NT;
    for (int f = tid; f < NFREQ; f += 256) d1[(size_t)f * NT + t] = buf[f];
  }
}

// ---------------- power ----------------
__global__ void power_kernel(const float2* __restrict__ mxs, float* __restrict__ power) {
  int i = blockIdx.x * 256 + threadIdx.x;
  if (i >= NB * NFREQ * NT) return;
  int b = i / (NFREQ * NT);
  int r = i - b * (NFREQ * NT);
  float acc = 0.0f;
#pragma unroll
  for (int c = 0; c < NCHN; ++c) {
    float2 v = mxs[(size_t)(b * NCHN + c) * NFREQ * NT + r];
    acc += v.x * v.x + v.y * v.y;
  }
  power[i] = acc * (1.0f / (float)NCHN);
}

// ---------------- per-batch max ----------------
__global__ void max_kernel(const float* __restrict__ power, float* __restrict__ mx) {
  int b = blockIdx.x;
  const float* p = power + (size_t)b * NFREQ * NT;
  float m = 0.0f;
  for (int i = threadIdx.x; i < NFREQ * NT; i += 256) m = fmaxf(m, p[i]);
#pragma unroll
  for (int off = 32; off > 0; off >>= 1) m = fmaxf(m, __shfl_down(m, off, 64));
  __shared__ float sm[4];
  int wave = threadIdx.x >> 6, lane = threadIdx.x & 63;
  if (lane == 0) sm[wave] = m;
  __syncthreads();
  if (threadIdx.x == 0) mx[b] = fmaxf(fmaxf(sm[0], sm[1]), fmaxf(sm[2], sm[3]));
}

// ---------------- R / P accumulation (fp32, Hermitian R, t-pair unrolled) ----------------
// grid: NG blocks, 384 threads. Threads 0-209: R lower triangle. 256-375: P.
// Ypad has 19 leading zeros -> no t0 boundary logic (zero terms are exact).
// Adjacent Ypad[t]/Ypad[t+1] loads merge into ds_read2_b64 (halves LDS instrs).
__global__ void rp_kernel(const float2* __restrict__ sph, const float2* __restrict__ mxs,
                          const float* __restrict__ power, const float* __restrict__ mx,
                          float2* __restrict__ R, float2* __restrict__ P) {
  __shared__ float2 Ypad[TAPS - 1 + NT];   // [0..18]=0, [19+u]=Y[u]
  __shared__ float2 MWsh[NCHN][NT];        // w[t] * conj(M[c][t])
  __shared__ float Wsh[NT];
  int g = blockIdx.x;
  int s = g & 1;
  int bf = g >> 1;
  int f = bf % NFREQ;
  int b = bf / NFREQ;
  int tid = threadIdx.x;

  const float2* yrow = sph + ((size_t)(b * NSPK + s) * NFREQ + f) * NT;
  const float* prow = power + ((size_t)b * NFREQ + f) * NT;
  float add = mx[b] * FCP_EPS_F + 1e-6f;
  for (int t = tid; t < NT; t += 384) Wsh[t] = 1.0f / (prow[t] + add);
  for (int i = tid; i < TAPS - 1 + NT; i += 384)
    Ypad[i] = (i < TAPS - 1) ? make_float2(0.0f, 0.0f) : yrow[i - (TAPS - 1)];
  __syncthreads();
  for (int i = tid; i < NCHN * NT; i += 384) {
    int c = i / NT, t = i - c * NT;
    float2 m = mxs[((size_t)(b * NCHN + c) * NFREQ + f) * NT + t];
    float w = Wsh[t];
    MWsh[c][t] = make_float2(w * m.x, -w * m.y);
  }
  __syncthreads();

  const float invT = 1.0f / (float)NT;
  if (tid < TAPS * (TAPS + 1) / 2) {
    int p = (int)((sqrtf(8.0f * (float)tid + 1.0f) - 1.0f) * 0.5f);
    while ((p + 1) * (p + 2) / 2 <= tid) ++p;
    while (p * (p + 1) / 2 > tid) --p;
    int q = tid - p * (p + 1) / 2;
    const float2* Ya = &Ypad[p];
    const float2* Yb = &Ypad[q];
    float ax0 = 0.0f, ay0 = 0.0f, ax1 = 0.0f, ay1 = 0.0f;
    int t = 0;
    for (; t + 1 < NT; t += 2) {
      float w0 = Wsh[t], w1 = Wsh[t + 1];
      float2 a0 = Ya[t], a1 = Ya[t + 1];
      float2 b0 = Yb[t], b1 = Yb[t + 1];
      ax0 = fmaf(w0, a0.x * b0.x + a0.y * b0.y, ax0);
      ay0 = fmaf(w0, a0.y * b0.x - a0.x * b0.y, ay0);
      ax1 = fmaf(w1, a1.x * b1.x + a1.y * b1.y, ax1);
      ay1 = fmaf(w1, a1.y * b1.x - a1.x * b1.y, ay1);
    }
    {  // t == 504 epilogue
      float w0 = Wsh[t];
      float2 a0 = Ya[t], b0 = Yb[t];
      ax0 = fmaf(w0, a0.x * b0.x + a0.y * b0.y, ax0);
      ay0 = fmaf(w0, a0.y * b0.x - a0.x * b0.y, ay0);
    }
    float ax = (ax0 + ax1) * invT, ay = (ay0 + ay1) * invT;
    R[(size_t)g * TAPS * TAPS + p * TAPS + q] = make_float2(ax, ay);
    R[(size_t)g * TAPS * TAPS + q * TAPS + p] = make_float2(ax, -ay);
  } else if (tid >= 256 && tid < 256 + TAPS * NCHN) {
    int i = tid - 256;
    int p = i / NCHN, c = i - p * NCHN;
    const float2* Ya = &Ypad[p];
    const float2* MW = &MWsh[c][0];
    float ax0 = 0.0f, ay0 = 0.0f, ax1 = 0.0f, ay1 = 0.0f;
    int t = 0;
    for (; t + 1 < NT; t += 2) {
      float2 a0 = Ya[t], a1 = Ya[t + 1];
      float2 m0 = MW[t], m1 = MW[t + 1];
      ax0 += a0.x * m0.x - a0.y * m0.y;
      ay0 += a0.x * m0.y + a0.y * m0.x;
      ax1 += a1.x * m1.x - a1.y * m1.y;
      ay1 += a1.x * m1.y + a1.y * m1.x;
    }
    {
      float2 a0 = Ya[t], m0 = MW[t];
      ax0 += a0.x * m0.x - a0.y * m0.y;
      ay0 += a0.x * m0.y + a0.y * m0.x;
    }
    P[(size_t)g * TAPS * NCHN + i] = make_float2((ax0 + ax1) * invT, (ay0 + ay1) * invT);
  }
}

// ---------------- LU solve with partial pivoting (complex128) ----------------
__global__ void solve_kernel(const float2* __restrict__ R, const float2* __restrict__ P,
                             float* __restrict__ gout, float2* __restrict__ gct) {
  __shared__ double2 A[TAPS][TAPS];
  __shared__ double2 Bm[TAPS][NCHN];
  __shared__ int piv;
  int g = blockIdx.x;
  int tid = threadIdx.x;
  int s = g & 1;
  int bf = g >> 1;
  int f = bf % NFREQ;
  int b = bf / NFREQ;
  int bs = b * NSPK + s;

  for (int i = tid; i < TAPS * TAPS; i += 64) {
    float2 r = R[(size_t)g * TAPS * TAPS + i];
    A[i / TAPS][i % TAPS] = make_double2((double)r.x, (double)r.y);
  }
  for (int i = tid; i < TAPS * NCHN; i += 64) {
    float2 p = P[(size_t)g * TAPS * NCHN + i];
    Bm[i / NCHN][i % NCHN] = make_double2((double)p.x, (double)p.y);
  }
  __syncthreads();
  if (tid < TAPS) A[tid][tid].x += LAMBDA_REG;
  __syncthreads();

  for (int k = 0; k < TAPS; ++k) {
    if (tid == 0) {
      int r = k;
      double best = fabs(A[k][k].x) + fabs(A[k][k].y);
      for (int i = k + 1; i < TAPS; ++i) {
        double v = fabs(A[i][k].x) + fabs(A[i][k].y);
        if (v > best) { best = v; r = i; }
      }
      piv = r;
    }
    __syncthreads();
    int r = piv;
    if (r != k) {
      if (tid < TAPS) {
        double2 tmp = A[k][tid]; A[k][tid] = A[r][tid]; A[r][tid] = tmp;
      } else if (tid < TAPS + NCHN) {
        int c = tid - TAPS;
        double2 tmp = Bm[k][c]; Bm[k][c] = Bm[r][c]; Bm[r][c] = tmp;
      }
    }
    __syncthreads();
    double2 akk = A[k][k];
    double den = akk.x * akk.x + akk.y * akk.y;
    if (tid > k && tid < TAPS) {
      double2 a = A[tid][k];
      A[tid][k] = make_double2((a.x * akk.x + a.y * akk.y) / den,
                               (a.y * akk.x - a.x * akk.y) / den);
    }
    __syncthreads();
    int nr = TAPS - 1 - k;
    int nc = nr + NCHN;
    for (int idx = tid; idx < nr * nc; idx += 64) {
      int i = k + 1 + idx / nc;
      int jj = idx % nc;
      double2 mlt = A[i][k];
      if (jj < nr) {
        int j = k + 1 + jj;
        double2 u = A[k][j];
        A[i][j].x -= mlt.x * u.x - mlt.y * u.y;
        A[i][j].y -= mlt.x * u.y + mlt.y * u.x;
      } else {
        int c = jj - nr;
        double2 u = Bm[k][c];
        Bm[i][c].x -= mlt.x * u.x - mlt.y * u.y;
        Bm[i][c].y -= mlt.x * u.y + mlt.y * u.x;
      }
    }
    __syncthreads();
  }

  if (tid < NCHN) {
    int c = tid;
    for (int k = TAPS - 1; k >= 0; --k) {
      double sx = Bm[k][c].x, sy = Bm[k][c].y;
      for (int j = k + 1; j < TAPS; ++j) {
        double2 u = A[k][j], xv = Bm[j][c];
        sx -= u.x * xv.x - u.y * xv.y;
        sy -= u.x * xv.y + u.y * xv.x;
      }
      double2 akk = A[k][k];
      double den = akk.x * akk.x + akk.y * akk.y;
      Bm[k][c] = make_double2((sx * akk.x + sy * akk.y) / den,
                              (sy * akk.x - sx * akk.y) / den);
    }
  }
  __syncthreads();

  for (int i = tid; i < TAPS * NCHN; i += 64) {
    int p = i / NCHN, c = i - p * NCHN;
    double2 gv = Bm[p][c];
    float gx = (float)gv.x, gy = (float)(-gv.y);  // conj(G)
    gout[(size_t)g * TAPS * NCHN + i] = gx;       // float32, real part only
    gct[(((size_t)bs * TAPS + p) * NCHN + c) * NFREQ + f] = make_float2(gx, gy);
  }
}

// ---------------- ret + inverse FFT (fused, XCD-swizzled) ----------------
// grid: NSIG*NT blocks (24240 % 8 == 0 -> simple swizzle is bijective).
// Contiguous (sc,t) chunks land on one XCD: spht slice + G slab fit its 4MB L2.
__global__ void ret_ifft_kernel(const float2* __restrict__ spht, const float2* __restrict__ gct,
                                float* __restrict__ frames) {
  __shared__ float2 buf[NFFT];
  constexpr int CPX = NSIG * NT / 8;
  int bid = blockIdx.x;
  int blk = (bid & 7) * CPX + (bid >> 3);  // XCD-aware swizzle
  int t = blk % NT;
  int sc = blk / NT;
  int c = sc % NCHN;
  int bs = sc / NCHN;
  int tid = threadIdx.x;

  int p0 = max(0, (TAPS - 1) - t);
  const float2* ybase = spht + ((size_t)bs * NT + (t - (TAPS - 1))) * NFREQ;
  const float2* gbase = gct + ((size_t)bs * TAPS * NCHN + c) * NFREQ;
  for (int f = tid; f < NFREQ; f += 256) {
    float sx = 0.0f, sy = 0.0f;
    for (int p = p0; p < TAPS; ++p) {
      float2 y = ybase[(size_t)p * NFREQ + f];
      float2 gc = gbase[(size_t)p * NCHN * NFREQ + f];
      sx += y.x * gc.x - y.y * gc.y;
      sy += y.x * gc.y + y.y * gc.x;
    }
    buf[rev9(f)] = make_float2(sx, sy);
    if (f > 0 && f < NFFT / 2) buf[rev9(NFFT - f)] = make_float2(sx, -sy);
  }
  __syncthreads();
  fft512(buf, tid, +1.0f);

  float* frow = frames + ((size_t)sc * NT + t) * NFFT;
  for (int n = tid; n < NFFT; n += 256) {
    float w = __sinf(PI_F * (float)n / (float)NFFT);
    frow[n] = buf[n].x * (1.0f / (float)NFFT) * w;
  }
}

// ---------------- overlap-add + env normalize + crop (float32 out) ----------------
// Interior samples: 4 overlapping sin^2 windows sum to exactly 2.
__global__ void ola_kernel(const float* __restrict__ frames, float* __restrict__ out) {
  int i = blockIdx.x * 256 + threadIdx.x;
  if (i >= NSIG * LSIG) return;
  int sig = i / LSIG;
  int l = i - sig * LSIG;
  int lp = l + NFFT / 2;
  int j0 = max(0, (lp - (NFFT - HOPSZ)) / HOPSZ);
  int j1 = min(NT - 1, lp / HOPSZ);
  float acc = 0.0f;
  for (int j = j0; j <= j1; ++j) {
    int n = lp - j * HOPSZ;
    acc += frames[((size_t)sig * NT + j) * NFFT + n];
  }
  float env;
  if (j1 - j0 == 3) {
    env = 2.0f;  // sum sin^2(theta + k*pi/4), k=0..3 == 2 exactly
  } else {
    env = 0.0f;
    for (int j = j0; j <= j1; ++j) {
      int n = lp - j * HOPSZ;
      float w = __sinf(PI_F * (float)n / (float)NFFT);
      env += w * w;
    }
    if (env <= 1e-11f) env = 1.0f;
  }
  out[(size_t)G_ELEMS + i] = acc / env;
}

}  // namespace

extern "C" void kernel_launch(void* const* d_in, const int* in_sizes, int n_in,
                              void* d_out, int out_size, void* d_ws, size_t ws_size,
                              hipStream_t stream) {
  const float* ref = (const float*)d_in[0];
  const float* mix = (const float*)d_in[1];
  if (n_in >= 2 && in_sizes[0] > in_sizes[1]) {
    const float* tmp = ref; ref = mix; mix = tmp;
  }
  char* ws = (char*)d_ws;

  float2*  sph   = (float2*)(ws + SPH_B);
  float2*  spht  = (float2*)(ws + SPHT_B);
  float2*  mxs   = (float2*)(ws + MXS_B);
  float*   power = (float*)(ws + POW_B);
  float*   mx    = (float*)(ws + MX_B);
  float2*  R     = (float2*)(ws + R_B);
  float2*  P     = (float2*)(ws + P_B);
  float2*  gct   = (float2*)(ws + GCT_B);
  float*   frames= (float*)(ws + FRM_B);
  float*   out   = (float*)d_out;

  stft_kernel<<<dim3((NB * NSPK + NB * NCHN) * NT), dim3(256), 0, stream>>>(ref, mix, sph, spht, mxs);
  power_kernel<<<dim3((NB * NFREQ * NT + 255) / 256), dim3(256), 0, stream>>>(mxs, power);
  max_kernel<<<dim3(NB), dim3(256), 0, stream>>>(power, mx);
  rp_kernel<<<dim3(NG), dim3(384), 0, stream>>>(sph, mxs, power, mx, R, P);
  solve_kernel<<<dim3(NG), dim3(64), 0, stream>>>(R, P, out, gct);
  ret_ifft_kernel<<<dim3(NSIG * NT), dim3(256), 0, stream>>>(spht, gct, frames);
  ola_kernel<<<dim3((NSIG * LSIG + 255) / 256), dim3(256), 0, stream>>>(frames, out);
}

// Round 11
// 406.238 us; speedup vs baseline: 1.3876x; 1.2369x over previous
//
#include <hip/hip_runtime.h>
#include <math.h>

namespace {

constexpr int NB = 4, NSPK = 2, NCHN = 6;
constexpr int LSIG = 64000;
constexpr int NFFT = 512, HOPSZ = 128, NFREQ = 257;
constexpr int NT = 505;               // frames
constexpr int TAPS = 20;
constexpr int NG = NB * NFREQ * NSPK; // 2056 systems
constexpr int NSIG = NB * NSPK * NCHN; // 48 istft signals
constexpr float PI_F = 3.14159265358979323846f;
constexpr double LAMBDA_REG = 2e-4;
constexpr float FCP_EPS_F = 1e-3f;
constexpr int G_ELEMS = NG * TAPS * NCHN; // 246720 floats (real part only)
constexpr int NCH2 = (NT + 1) / 2;    // 253 two-frame chunks (last is single)

constexpr size_t WS_ALIGN = 256;
constexpr size_t align_up(size_t x) { return (x + WS_ALIGN - 1) & ~(WS_ALIGN - 1); }

// ws byte offsets
constexpr size_t SPH_B  = 0;                                        // [8][257][505] float2
constexpr size_t SPH_SZ = (size_t)NB * NSPK * NFREQ * NT * 8;
constexpr size_t SPHT_B = align_up(SPH_B + SPH_SZ);                 // [8][505][257] float2
constexpr size_t MXS_B  = align_up(SPHT_B + SPH_SZ);                // [24][257][505] float2
constexpr size_t MXS_SZ = (size_t)NB * NCHN * NFREQ * NT * 8;
constexpr size_t POW_B  = align_up(MXS_B + MXS_SZ);                 // [4][257][505] float
constexpr size_t POW_SZ = (size_t)NB * NFREQ * NT * 4;
constexpr size_t MX_B   = align_up(POW_B + POW_SZ);                 // [4] float
constexpr size_t R_B    = align_up(MX_B + (size_t)NB * 4);          // [2056][400] float2
constexpr size_t R_SZ   = (size_t)NG * TAPS * TAPS * 8;
constexpr size_t P_B    = align_up(R_B + R_SZ);                     // [2056][120] float2
constexpr size_t P_SZ   = (size_t)NG * TAPS * NCHN * 8;
constexpr size_t GCT_B  = align_up(P_B + P_SZ);                     // [8][20][6][257] float2
constexpr size_t GCT_SZ = (size_t)NB * NSPK * TAPS * NCHN * NFREQ * 8;
constexpr size_t FRM_B  = align_up(GCT_B + GCT_SZ);                 // [48][505][512] float

__device__ __forceinline__ int rev9(int n) { return (int)(__brev((unsigned)n) >> 23); }

// Dual in-LDS radix-2 DIT FFT: TWO independent 512-point transforms in
// buf[0..511] and buf[512..1023]. Same butterfly indices -> twiddle computed
// once, 2 butterflies/thread/stage, barrier cost amortized 2x.
__device__ __forceinline__ void fft512_dual(float2* buf, int tid, float sign) {
#pragma unroll
  for (int s = 1; s <= 9; ++s) {
    int half = 1 << (s - 1);
    int blk = tid >> (s - 1);
    int pos = tid & (half - 1);
    int i0 = (blk << s) + pos;
    int i1 = i0 + half;
    float ang = sign * 2.0f * PI_F * (float)pos / (float)(half << 1);
    float sn, cs;
    __sincosf(ang, &sn, &cs);
    {
      float2 u = buf[i0], v = buf[i1];
      float2 vw = make_float2(v.x * cs - v.y * sn, v.x * sn + v.y * cs);
      buf[i0] = make_float2(u.x + vw.x, u.y + vw.y);
      buf[i1] = make_float2(u.x - vw.x, u.y - vw.y);
    }
    {
      float2 u = buf[NFFT + i0], v = buf[NFFT + i1];
      float2 vw = make_float2(v.x * cs - v.y * sn, v.x * sn + v.y * cs);
      buf[NFFT + i0] = make_float2(u.x + vw.x, u.y + vw.y);
      buf[NFFT + i1] = make_float2(u.x - vw.x, u.y - vw.y);
    }
    __syncthreads();
  }
}

// ---------------- STFT (dual-frame radix-2 FFT) ----------------
// grid: 32 * NCH2 blocks, 256 threads. Frames t0=2*ch, t0+1 per block.
__global__ void stft_kernel(const float* __restrict__ ref, const float* __restrict__ mix,
                            float2* __restrict__ sph, float2* __restrict__ spht,
                            float2* __restrict__ mxs) {
  __shared__ float2 buf[2 * NFFT];
  int blk = blockIdx.x;
  int sig = blk / NCH2;
  int ch = blk - sig * NCH2;
  int t0 = ch * 2;
  bool dual = (t0 + 1 < NT);
  int tid = threadIdx.x;
  bool is_ref = sig < NB * NSPK;
  int m = is_ref ? sig : (sig - NB * NSPK);
  const float* src = is_ref ? (ref + (size_t)m * LSIG) : (mix + (size_t)m * LSIG);

  for (int n = tid; n < NFFT; n += 256) {
    float w = __sinf(PI_F * (float)n / (float)NFFT);  // sqrt-hann
    int g0 = t0 * HOPSZ + n - NFFT / 2;
    float v0 = (g0 >= 0 && g0 < LSIG) ? src[g0] : 0.0f;
    int g1 = g0 + HOPSZ;
    float v1 = (dual && g1 >= 0 && g1 < LSIG) ? src[g1] : 0.0f;
    int r = rev9(n);
    buf[r] = make_float2(v0 * w, 0.0f);
    buf[NFFT + r] = make_float2(v1 * w, 0.0f);
  }
  __syncthreads();
  fft512_dual(buf, tid, -1.0f);

  if (is_ref) {
    float2* d1 = sph + (size_t)m * NFREQ * NT;
    float2* d2 = spht + ((size_t)m * NT + t0) * NFREQ;
    for (int f = tid; f < NFREQ; f += 256) {
      float2 v0 = buf[f], v1 = buf[NFFT + f];
      d1[(size_t)f * NT + t0] = v0;
      d2[f] = v0;
      if (dual) {
        d1[(size_t)f * NT + t0 + 1] = v1;
        d2[NFREQ + f] = v1;
      }
    }
  } else {
    float2* d1 = mxs + (size_t)m * NFREQ * NT;
    for (int f = tid; f < NFREQ; f += 256) {
      d1[(size_t)f * NT + t0] = buf[f];
      if (dual) d1[(size_t)f * NT + t0 + 1] = buf[NFFT + f];
    }
  }
}

// ---------------- power ----------------
__global__ void power_kernel(const float2* __restrict__ mxs, float* __restrict__ power) {
  int i = blockIdx.x * 256 + threadIdx.x;
  if (i >= NB * NFREQ * NT) return;
  int b = i / (NFREQ * NT);
  int r = i - b * (NFREQ * NT);
  float acc = 0.0f;
#pragma unroll
  for (int c = 0; c < NCHN; ++c) {
    float2 v = mxs[(size_t)(b * NCHN + c) * NFREQ * NT + r];
    acc += v.x * v.x + v.y * v.y;
  }
  power[i] = acc * (1.0f / (float)NCHN);
}

// ---------------- per-batch max ----------------
__global__ void max_kernel(const float* __restrict__ power, float* __restrict__ mx) {
  int b = blockIdx.x;
  const float* p = power + (size_t)b * NFREQ * NT;
  float m = 0.0f;
  for (int i = threadIdx.x; i < NFREQ * NT; i += 256) m = fmaxf(m, p[i]);
#pragma unroll
  for (int off = 32; off > 0; off >>= 1) m = fmaxf(m, __shfl_down(m, off, 64));
  __shared__ float sm[4];
  int wave = threadIdx.x >> 6, lane = threadIdx.x & 63;
  if (lane == 0) sm[wave] = m;
  __syncthreads();
  if (threadIdx.x == 0) mx[b] = fmaxf(fmaxf(sm[0], sm[1]), fmaxf(sm[2], sm[3]));
}

// ---------------- R / P accumulation (fp32, Hermitian R, t-pair unrolled) ----------------
__global__ void rp_kernel(const float2* __restrict__ sph, const float2* __restrict__ mxs,
                          const float* __restrict__ power, const float* __restrict__ mx,
                          float2* __restrict__ R, float2* __restrict__ P) {
  __shared__ float2 Ypad[TAPS - 1 + NT];   // [0..18]=0, [19+u]=Y[u]
  __shared__ float2 MWsh[NCHN][NT];        // w[t] * conj(M[c][t])
  __shared__ float Wsh[NT];
  int g = blockIdx.x;
  int s = g & 1;
  int bf = g >> 1;
  int f = bf % NFREQ;
  int b = bf / NFREQ;
  int tid = threadIdx.x;

  const float2* yrow = sph + ((size_t)(b * NSPK + s) * NFREQ + f) * NT;
  const float* prow = power + ((size_t)b * NFREQ + f) * NT;
  float add = mx[b] * FCP_EPS_F + 1e-6f;
  for (int t = tid; t < NT; t += 384) Wsh[t] = 1.0f / (prow[t] + add);
  for (int i = tid; i < TAPS - 1 + NT; i += 384)
    Ypad[i] = (i < TAPS - 1) ? make_float2(0.0f, 0.0f) : yrow[i - (TAPS - 1)];
  __syncthreads();
  for (int i = tid; i < NCHN * NT; i += 384) {
    int c = i / NT, t = i - c * NT;
    float2 m = mxs[((size_t)(b * NCHN + c) * NFREQ + f) * NT + t];
    float w = Wsh[t];
    MWsh[c][t] = make_float2(w * m.x, -w * m.y);
  }
  __syncthreads();

  const float invT = 1.0f / (float)NT;
  if (tid < TAPS * (TAPS + 1) / 2) {
    int p = (int)((sqrtf(8.0f * (float)tid + 1.0f) - 1.0f) * 0.5f);
    while ((p + 1) * (p + 2) / 2 <= tid) ++p;
    while (p * (p + 1) / 2 > tid) --p;
    int q = tid - p * (p + 1) / 2;
    const float2* Ya = &Ypad[p];
    const float2* Yb = &Ypad[q];
    float ax0 = 0.0f, ay0 = 0.0f, ax1 = 0.0f, ay1 = 0.0f;
    int t = 0;
    for (; t + 1 < NT; t += 2) {
      float w0 = Wsh[t], w1 = Wsh[t + 1];
      float2 a0 = Ya[t], a1 = Ya[t + 1];
      float2 b0 = Yb[t], b1 = Yb[t + 1];
      ax0 = fmaf(w0, a0.x * b0.x + a0.y * b0.y, ax0);
      ay0 = fmaf(w0, a0.y * b0.x - a0.x * b0.y, ay0);
      ax1 = fmaf(w1, a1.x * b1.x + a1.y * b1.y, ax1);
      ay1 = fmaf(w1, a1.y * b1.x - a1.x * b1.y, ay1);
    }
    {
      float w0 = Wsh[t];
      float2 a0 = Ya[t], b0 = Yb[t];
      ax0 = fmaf(w0, a0.x * b0.x + a0.y * b0.y, ax0);
      ay0 = fmaf(w0, a0.y * b0.x - a0.x * b0.y, ay0);
    }
    float ax = (ax0 + ax1) * invT, ay = (ay0 + ay1) * invT;
    R[(size_t)g * TAPS * TAPS + p * TAPS + q] = make_float2(ax, ay);
    R[(size_t)g * TAPS * TAPS + q * TAPS + p] = make_float2(ax, -ay);
  } else if (tid >= 256 && tid < 256 + TAPS * NCHN) {
    int i = tid - 256;
    int p = i / NCHN, c = i - p * NCHN;
    const float2* Ya = &Ypad[p];
    const float2* MW = &MWsh[c][0];
    float ax0 = 0.0f, ay0 = 0.0f, ax1 = 0.0f, ay1 = 0.0f;
    int t = 0;
    for (; t + 1 < NT; t += 2) {
      float2 a0 = Ya[t], a1 = Ya[t + 1];
      float2 m0 = MW[t], m1 = MW[t + 1];
      ax0 += a0.x * m0.x - a0.y * m0.y;
      ay0 += a0.x * m0.y + a0.y * m0.x;
      ax1 += a1.x * m1.x - a1.y * m1.y;
      ay1 += a1.x * m1.y + a1.y * m1.x;
    }
    {
      float2 a0 = Ya[t], m0 = MW[t];
      ax0 += a0.x * m0.x - a0.y * m0.y;
      ay0 += a0.x * m0.y + a0.y * m0.x;
    }
    P[(size_t)g * TAPS * NCHN + i] = make_float2((ax0 + ax1) * invT, (ay0 + ay1) * invT);
  }
}

// ---------------- LU solve with partial pivoting (complex128) ----------------
__global__ void solve_kernel(const float2* __restrict__ R, const float2* __restrict__ P,
                             float* __restrict__ gout, float2* __restrict__ gct) {
  __shared__ double2 A[TAPS][TAPS];
  __shared__ double2 Bm[TAPS][NCHN];
  __shared__ int piv;
  int g = blockIdx.x;
  int tid = threadIdx.x;
  int s = g & 1;
  int bf = g >> 1;
  int f = bf % NFREQ;
  int b = bf / NFREQ;
  int bs = b * NSPK + s;

  for (int i = tid; i < TAPS * TAPS; i += 64) {
    float2 r = R[(size_t)g * TAPS * TAPS + i];
    A[i / TAPS][i % TAPS] = make_double2((double)r.x, (double)r.y);
  }
  for (int i = tid; i < TAPS * NCHN; i += 64) {
    float2 p = P[(size_t)g * TAPS * NCHN + i];
    Bm[i / NCHN][i % NCHN] = make_double2((double)p.x, (double)p.y);
  }
  __syncthreads();
  if (tid < TAPS) A[tid][tid].x += LAMBDA_REG;
  __syncthreads();

  for (int k = 0; k < TAPS; ++k) {
    if (tid == 0) {
      int r = k;
      double best = fabs(A[k][k].x) + fabs(A[k][k].y);
      for (int i = k + 1; i < TAPS; ++i) {
        double v = fabs(A[i][k].x) + fabs(A[i][k].y);
        if (v > best) { best = v; r = i; }
      }
      piv = r;
    }
    __syncthreads();
    int r = piv;
    if (r != k) {
      if (tid < TAPS) {
        double2 tmp = A[k][tid]; A[k][tid] = A[r][tid]; A[r][tid] = tmp;
      } else if (tid < TAPS + NCHN) {
        int c = tid - TAPS;
        double2 tmp = Bm[k][c]; Bm[k][c] = Bm[r][c]; Bm[r][c] = tmp;
      }
    }
    __syncthreads();
    double2 akk = A[k][k];
    double den = akk.x * akk.x + akk.y * akk.y;
    if (tid > k && tid < TAPS) {
      double2 a = A[tid][k];
      A[tid][k] = make_double2((a.x * akk.x + a.y * akk.y) / den,
                               (a.y * akk.x - a.x * akk.y) / den);
    }
    __syncthreads();
    int nr = TAPS - 1 - k;
    int nc = nr + NCHN;
    for (int idx = tid; idx < nr * nc; idx += 64) {
      int i = k + 1 + idx / nc;
      int jj = idx % nc;
      double2 mlt = A[i][k];
      if (jj < nr) {
        int j = k + 1 + jj;
        double2 u = A[k][j];
        A[i][j].x -= mlt.x * u.x - mlt.y * u.y;
        A[i][j].y -= mlt.x * u.y + mlt.y * u.x;
      } else {
        int c = jj - nr;
        double2 u = Bm[k][c];
        Bm[i][c].x -= mlt.x * u.x - mlt.y * u.y;
        Bm[i][c].y -= mlt.x * u.y + mlt.y * u.x;
      }
    }
    __syncthreads();
  }

  if (tid < NCHN) {
    int c = tid;
    for (int k = TAPS - 1; k >= 0; --k) {
      double sx = Bm[k][c].x, sy = Bm[k][c].y;
      for (int j = k + 1; j < TAPS; ++j) {
        double2 u = A[k][j], xv = Bm[j][c];
        sx -= u.x * xv.x - u.y * xv.y;
        sy -= u.x * xv.y + u.y * xv.x;
      }
      double2 akk = A[k][k];
      double den = akk.x * akk.x + akk.y * akk.y;
      Bm[k][c] = make_double2((sx * akk.x + sy * akk.y) / den,
                              (sy * akk.x - sx * akk.y) / den);
    }
  }
  __syncthreads();

  for (int i = tid; i < TAPS * NCHN; i += 64) {
    int p = i / NCHN, c = i - p * NCHN;
    double2 gv = Bm[p][c];
    float gx = (float)gv.x, gy = (float)(-gv.y);  // conj(G)
    gout[(size_t)g * TAPS * NCHN + i] = gx;       // float32, real part only
    gct[(((size_t)bs * TAPS + p) * NCHN + c) * NFREQ + f] = make_float2(gx, gy);
  }
}

// ---------------- ret + inverse FFT (dual-frame, XCD-swizzled) ----------------
// grid: NSIG*NCH2 = 12144 blocks (%8==0). Frames t0=2*ch, t0+1 share 19 Y rows
// and all 20 G rows: merged 21-iter loop does 41 loads for 2 spectra.
__global__ void ret_ifft_kernel(const float2* __restrict__ spht, const float2* __restrict__ gct,
                                float* __restrict__ frames) {
  __shared__ float2 buf[2 * NFFT];
  constexpr int NBLK = NSIG * NCH2;
  int bid = blockIdx.x;
  int blk = (bid & 7) * (NBLK / 8) + (bid >> 3);  // XCD-aware swizzle
  int ch = blk % NCH2;
  int sc = blk / NCH2;
  int t0 = ch * 2;
  bool dual = (t0 + 1 < NT);
  int c = sc % NCHN;
  int bs = sc / NCHN;
  int tid = threadIdx.x;

  const float2* gbase = gct + ((size_t)bs * TAPS * NCHN + c) * NFREQ;
  const float2* ysig = spht + (size_t)bs * NT * NFREQ;
  for (int f = tid; f < NFREQ; f += 256) {
    float sx0 = 0.0f, sy0 = 0.0f, sx1 = 0.0f, sy1 = 0.0f;
    float2 gprev = make_float2(0.0f, 0.0f);
#pragma unroll
    for (int k = 0; k <= TAPS; ++k) {  // k = p(frame0); p(frame1) = k-1
      int u = t0 - (TAPS - 1) + k;
      float2 y = (u >= 0 && u < NT) ? ysig[(size_t)u * NFREQ + f] : make_float2(0.0f, 0.0f);
      float2 gc = (k < TAPS) ? gbase[(size_t)k * NCHN * NFREQ + f] : make_float2(0.0f, 0.0f);
      if (k < TAPS) {
        sx0 += y.x * gc.x - y.y * gc.y;
        sy0 += y.x * gc.y + y.y * gc.x;
      }
      if (k >= 1) {
        sx1 += y.x * gprev.x - y.y * gprev.y;
        sy1 += y.x * gprev.y + y.y * gprev.x;
      }
      gprev = gc;
    }
    int r = rev9(f);
    buf[r] = make_float2(sx0, sy0);
    buf[NFFT + r] = make_float2(sx1, sy1);
    if (f > 0 && f < NFFT / 2) {
      int r2 = rev9(NFFT - f);
      buf[r2] = make_float2(sx0, -sy0);
      buf[NFFT + r2] = make_float2(sx1, -sy1);
    }
  }
  __syncthreads();
  fft512_dual(buf, tid, +1.0f);

  float* frow = frames + ((size_t)sc * NT + t0) * NFFT;
  for (int n = tid; n < NFFT; n += 256) {
    float w = __sinf(PI_F * (float)n / (float)NFFT);
    frow[n] = buf[n].x * (1.0f / (float)NFFT) * w;
    if (dual) frow[NFFT + n] = buf[NFFT + n].x * (1.0f / (float)NFFT) * w;
  }
}

// ---------------- overlap-add + env normalize + crop (float32 out) ----------------
__global__ void ola_kernel(const float* __restrict__ frames, float* __restrict__ out) {
  int i = blockIdx.x * 256 + threadIdx.x;
  if (i >= NSIG * LSIG) return;
  int sig = i / LSIG;
  int l = i - sig * LSIG;
  int lp = l + NFFT / 2;
  int j0 = max(0, (lp - (NFFT - HOPSZ)) / HOPSZ);
  int j1 = min(NT - 1, lp / HOPSZ);
  float acc = 0.0f;
  for (int j = j0; j <= j1; ++j) {
    int n = lp - j * HOPSZ;
    acc += frames[((size_t)sig * NT + j) * NFFT + n];
  }
  float env;
  if (j1 - j0 == 3) {
    env = 2.0f;  // sum sin^2(theta + k*pi/4), k=0..3 == 2 exactly
  } else {
    env = 0.0f;
    for (int j = j0; j <= j1; ++j) {
      int n = lp - j * HOPSZ;
      float w = __sinf(PI_F * (float)n / (float)NFFT);
      env += w * w;
    }
    if (env <= 1e-11f) env = 1.0f;
  }
  out[(size_t)G_ELEMS + i] = acc / env;
}

}  // namespace

extern "C" void kernel_launch(void* const* d_in, const int* in_sizes, int n_in,
                              void* d_out, int out_size, void* d_ws, size_t ws_size,
                              hipStream_t stream) {
  const float* ref = (const float*)d_in[0];
  const float* mix = (const float*)d_in[1];
  if (n_in >= 2 && in_sizes[0] > in_sizes[1]) {
    const float* tmp = ref; ref = mix; mix = tmp;
  }
  char* ws = (char*)d_ws;

  float2*  sph   = (float2*)(ws + SPH_B);
  float2*  spht  = (float2*)(ws + SPHT_B);
  float2*  mxs   = (float2*)(ws + MXS_B);
  float*   power = (float*)(ws + POW_B);
  float*   mx    = (float*)(ws + MX_B);
  float2*  R     = (float2*)(ws + R_B);
  float2*  P     = (float2*)(ws + P_B);
  float2*  gct   = (float2*)(ws + GCT_B);
  float*   frames= (float*)(ws + FRM_B);
  float*   out   = (float*)d_out;

  stft_kernel<<<dim3((NB * NSPK + NB * NCHN) * NCH2), dim3(256), 0, stream>>>(ref, mix, sph, spht, mxs);
  power_kernel<<<dim3((NB * NFREQ * NT + 255) / 256), dim3(256), 0, stream>>>(mxs, power);
  max_kernel<<<dim3(NB), dim3(256), 0, stream>>>(power, mx);
  rp_kernel<<<dim3(NG), dim3(384), 0, stream>>>(sph, mxs, power, mx, R, P);
  solve_kernel<<<dim3(NG), dim3(64), 0, stream>>>(R, P, out, gct);
  ret_ifft_kernel<<<dim3(NSIG * NCH2), dim3(256), 0, stream>>>(spht, gct, frames);
  ola_kernel<<<dim3((NSIG * LSIG + 255) / 256), dim3(256), 0, stream>>>(frames, out);
}

// Round 12
// 403.611 us; speedup vs baseline: 1.3966x; 1.0065x over previous
//
#include <hip/hip_runtime.h>
#include <math.h>

namespace {

constexpr int NB = 4, NSPK = 2, NCHN = 6;
constexpr int LSIG = 64000;
constexpr int NFFT = 512, HOPSZ = 128, NFREQ = 257;
constexpr int NT = 505;               // frames
constexpr int TAPS = 20;
constexpr int NG = NB * NFREQ * NSPK; // 2056 systems
constexpr int NSIG = NB * NSPK * NCHN; // 48 istft signals
constexpr float PI_F = 3.14159265358979323846f;
constexpr double LAMBDA_REG = 2e-4;
constexpr float FCP_EPS_F = 1e-3f;
constexpr int G_ELEMS = NG * TAPS * NCHN; // 246720 floats (real part only)
constexpr int NCH2 = (NT + 1) / 2;    // 253 two-frame chunks (last is single)
constexpr int YPAD_N = TAPS + 2 + NT; // 527: [0..18]=0, [19+u]=Y[u], tail zeros

constexpr size_t WS_ALIGN = 256;
constexpr size_t align_up(size_t x) { return (x + WS_ALIGN - 1) & ~(WS_ALIGN - 1); }

// ws byte offsets
constexpr size_t SPH_B  = 0;                                        // [8][257][505] float2
constexpr size_t SPH_SZ = (size_t)NB * NSPK * NFREQ * NT * 8;
constexpr size_t SPHT_B = align_up(SPH_B + SPH_SZ);                 // [8][505][257] float2
constexpr size_t MXS_B  = align_up(SPHT_B + SPH_SZ);                // [24][257][505] float2
constexpr size_t MXS_SZ = (size_t)NB * NCHN * NFREQ * NT * 8;
constexpr size_t POW_B  = align_up(MXS_B + MXS_SZ);                 // [4][257][505] float
constexpr size_t POW_SZ = (size_t)NB * NFREQ * NT * 4;
constexpr size_t MX_B   = align_up(POW_B + POW_SZ);                 // [4] float
constexpr size_t R_B    = align_up(MX_B + (size_t)NB * 4);          // [2056][400] float2
constexpr size_t R_SZ   = (size_t)NG * TAPS * TAPS * 8;
constexpr size_t P_B    = align_up(R_B + R_SZ);                     // [2056][120] float2
constexpr size_t P_SZ   = (size_t)NG * TAPS * NCHN * 8;
constexpr size_t GCT_B  = align_up(P_B + P_SZ);                     // [8][20][6][257] float2
constexpr size_t GCT_SZ = (size_t)NB * NSPK * TAPS * NCHN * NFREQ * 8;
constexpr size_t FRM_B  = align_up(GCT_B + GCT_SZ);                 // [48][505][512] float

__device__ __forceinline__ int rev9(int n) { return (int)(__brev((unsigned)n) >> 23); }

// Dual in-LDS radix-2 DIT FFT (two independent 512-pt transforms).
__device__ __forceinline__ void fft512_dual(float2* buf, int tid, float sign) {
#pragma unroll
  for (int s = 1; s <= 9; ++s) {
    int half = 1 << (s - 1);
    int blk = tid >> (s - 1);
    int pos = tid & (half - 1);
    int i0 = (blk << s) + pos;
    int i1 = i0 + half;
    float ang = sign * 2.0f * PI_F * (float)pos / (float)(half << 1);
    float sn, cs;
    __sincosf(ang, &sn, &cs);
    {
      float2 u = buf[i0], v = buf[i1];
      float2 vw = make_float2(v.x * cs - v.y * sn, v.x * sn + v.y * cs);
      buf[i0] = make_float2(u.x + vw.x, u.y + vw.y);
      buf[i1] = make_float2(u.x - vw.x, u.y - vw.y);
    }
    {
      float2 u = buf[NFFT + i0], v = buf[NFFT + i1];
      float2 vw = make_float2(v.x * cs - v.y * sn, v.x * sn + v.y * cs);
      buf[NFFT + i0] = make_float2(u.x + vw.x, u.y + vw.y);
      buf[NFFT + i1] = make_float2(u.x - vw.x, u.y - vw.y);
    }
    __syncthreads();
  }
}

// ---------------- STFT (dual-frame radix-2 FFT) ----------------
__global__ void stft_kernel(const float* __restrict__ ref, const float* __restrict__ mix,
                            float2* __restrict__ sph, float2* __restrict__ spht,
                            float2* __restrict__ mxs) {
  __shared__ float2 buf[2 * NFFT];
  int blk = blockIdx.x;
  int sig = blk / NCH2;
  int ch = blk - sig * NCH2;
  int t0 = ch * 2;
  bool dual = (t0 + 1 < NT);
  int tid = threadIdx.x;
  bool is_ref = sig < NB * NSPK;
  int m = is_ref ? sig : (sig - NB * NSPK);
  const float* src = is_ref ? (ref + (size_t)m * LSIG) : (mix + (size_t)m * LSIG);

  for (int n = tid; n < NFFT; n += 256) {
    float w = __sinf(PI_F * (float)n / (float)NFFT);  // sqrt-hann
    int g0 = t0 * HOPSZ + n - NFFT / 2;
    float v0 = (g0 >= 0 && g0 < LSIG) ? src[g0] : 0.0f;
    int g1 = g0 + HOPSZ;
    float v1 = (dual && g1 >= 0 && g1 < LSIG) ? src[g1] : 0.0f;
    int r = rev9(n);
    buf[r] = make_float2(v0 * w, 0.0f);
    buf[NFFT + r] = make_float2(v1 * w, 0.0f);
  }
  __syncthreads();
  fft512_dual(buf, tid, -1.0f);

  if (is_ref) {
    float2* d1 = sph + (size_t)m * NFREQ * NT;
    float2* d2 = spht + ((size_t)m * NT + t0) * NFREQ;
    for (int f = tid; f < NFREQ; f += 256) {
      float2 v0 = buf[f], v1 = buf[NFFT + f];
      d1[(size_t)f * NT + t0] = v0;
      d2[f] = v0;
      if (dual) {
        d1[(size_t)f * NT + t0 + 1] = v1;
        d2[NFREQ + f] = v1;
      }
    }
  } else {
    float2* d1 = mxs + (size_t)m * NFREQ * NT;
    for (int f = tid; f < NFREQ; f += 256) {
      d1[(size_t)f * NT + t0] = buf[f];
      if (dual) d1[(size_t)f * NT + t0 + 1] = buf[NFFT + f];
    }
  }
}

// ---------------- power ----------------
__global__ void power_kernel(const float2* __restrict__ mxs, float* __restrict__ power) {
  int i = blockIdx.x * 256 + threadIdx.x;
  if (i >= NB * NFREQ * NT) return;
  int b = i / (NFREQ * NT);
  int r = i - b * (NFREQ * NT);
  float acc = 0.0f;
#pragma unroll
  for (int c = 0; c < NCHN; ++c) {
    float2 v = mxs[(size_t)(b * NCHN + c) * NFREQ * NT + r];
    acc += v.x * v.x + v.y * v.y;
  }
  power[i] = acc * (1.0f / (float)NCHN);
}

// ---------------- per-batch max ----------------
__global__ void max_kernel(const float* __restrict__ power, float* __restrict__ mx) {
  int b = blockIdx.x;
  const float* p = power + (size_t)b * NFREQ * NT;
  float m = 0.0f;
  for (int i = threadIdx.x; i < NFREQ * NT; i += 256) m = fmaxf(m, p[i]);
#pragma unroll
  for (int off = 32; off > 0; off >>= 1) m = fmaxf(m, __shfl_down(m, off, 64));
  __shared__ float sm[4];
  int wave = threadIdx.x >> 6, lane = threadIdx.x & 63;
  if (lane == 0) sm[wave] = m;
  __syncthreads();
  if (threadIdx.x == 0) mx[b] = fmaxf(fmaxf(sm[0], sm[1]), fmaxf(sm[2], sm[3]));
}

// ---------------- R / P accumulation (register-tiled sliding window) ----------------
// 256 threads. Wave 0: threads 0-54 = 2x2 (p,q) tiles of R's lower triangle.
// Wave 1: threads 64-123 = 2x1 p-tiles x 6 channels for P.
// Per t: R tile does 2 fresh LDS loads + 1 broadcast for 4 outputs (sliding
// window); P tile does 2 loads for 2 outputs. Single b64 reads, conflict-free.
__global__ void rp_kernel(const float2* __restrict__ sph, const float2* __restrict__ mxs,
                          const float* __restrict__ power, const float* __restrict__ mx,
                          float2* __restrict__ R, float2* __restrict__ P) {
  __shared__ float2 Ypad[YPAD_N];      // [0..18]=0, [19+u]=Y[u], tail zeros
  __shared__ float2 MWsh[NCHN][NT];    // w[t] * conj(M[c][t])
  __shared__ float Wsh[NT];
  int g = blockIdx.x;
  int s = g & 1;
  int bf = g >> 1;
  int f = bf % NFREQ;
  int b = bf / NFREQ;
  int tid = threadIdx.x;

  const float2* yrow = sph + ((size_t)(b * NSPK + s) * NFREQ + f) * NT;
  const float* prow = power + ((size_t)b * NFREQ + f) * NT;
  float add = mx[b] * FCP_EPS_F + 1e-6f;
  for (int t = tid; t < NT; t += 256) Wsh[t] = 1.0f / (prow[t] + add);
  for (int i = tid; i < YPAD_N; i += 256) {
    bool in = (i >= TAPS - 1) && (i < TAPS - 1 + NT);
    Ypad[i] = in ? yrow[i - (TAPS - 1)] : make_float2(0.0f, 0.0f);
  }
  __syncthreads();
  for (int i = tid; i < NCHN * NT; i += 256) {
    int c = i / NT, t = i - c * NT;
    float2 m = mxs[((size_t)(b * NCHN + c) * NFREQ + f) * NT + t];
    float w = Wsh[t];
    MWsh[c][t] = make_float2(w * m.x, -w * m.y);
  }
  __syncthreads();

  const float invT = 1.0f / (float)NT;
  if (tid < 55) {
    // tile (I,J), I>=J: rows p=2I,2I+1; cols q=2J,2J+1
    int I = (int)((sqrtf(8.0f * (float)tid + 1.0f) - 1.0f) * 0.5f);
    while ((I + 1) * (I + 2) / 2 <= tid) ++I;
    while (I * (I + 1) / 2 > tid) --I;
    int J = tid - I * (I + 1) / 2;
    int pb = 2 * I, qb = 2 * J;
    float2 a0 = Ypad[pb], a1 = Ypad[pb + 1];
    float2 b0 = Ypad[qb], b1 = Ypad[qb + 1];
    float x00 = 0.f, y00 = 0.f, x01 = 0.f, y01 = 0.f;
    float x10 = 0.f, y10 = 0.f, x11 = 0.f, y11 = 0.f;
    for (int t = 0; t < NT; ++t) {
      float w = Wsh[t];
      // acc(pq) += w * (a_p · conj(b_q))
      x00 = fmaf(w, a0.x * b0.x + a0.y * b0.y, x00);
      y00 = fmaf(w, a0.y * b0.x - a0.x * b0.y, y00);
      x01 = fmaf(w, a0.x * b1.x + a0.y * b1.y, x01);
      y01 = fmaf(w, a0.y * b1.x - a0.x * b1.y, y01);
      x10 = fmaf(w, a1.x * b0.x + a1.y * b0.y, x10);
      y10 = fmaf(w, a1.y * b0.x - a1.x * b0.y, y10);
      x11 = fmaf(w, a1.x * b1.x + a1.y * b1.y, x11);
      y11 = fmaf(w, a1.y * b1.x - a1.x * b1.y, y11);
      a0 = a1; a1 = Ypad[pb + 2 + t];   // slide window
      b0 = b1; b1 = Ypad[qb + 2 + t];
    }
    float2* Rg = R + (size_t)g * TAPS * TAPS;
#define STORE_R(p_, q_, xx, yy)                                   \
    if ((p_) >= (q_)) {                                            \
      float rx = (xx) * invT, ry = (yy) * invT;                    \
      Rg[(p_) * TAPS + (q_)] = make_float2(rx, ry);                \
      if ((p_) != (q_)) Rg[(q_) * TAPS + (p_)] = make_float2(rx, -ry); \
    }
    STORE_R(pb, qb, x00, y00)
    STORE_R(pb, qb + 1, x01, y01)
    STORE_R(pb + 1, qb, x10, y10)
    STORE_R(pb + 1, qb + 1, x11, y11)
#undef STORE_R
  } else if (tid >= 64 && tid < 64 + 10 * NCHN) {
    int i = tid - 64;
    int ih = i / NCHN, c = i - ih * NCHN;
    int pb = 2 * ih;
    float2 a0 = Ypad[pb], a1 = Ypad[pb + 1];
    float x0 = 0.f, y0 = 0.f, x1 = 0.f, y1 = 0.f;
    const float2* MW = &MWsh[c][0];
    for (int t = 0; t < NT; ++t) {
      float2 mw = MW[t];
      x0 += a0.x * mw.x - a0.y * mw.y;
      y0 += a0.x * mw.y + a0.y * mw.x;
      x1 += a1.x * mw.x - a1.y * mw.y;
      y1 += a1.x * mw.y + a1.y * mw.x;
      a0 = a1; a1 = Ypad[pb + 2 + t];
    }
    float2* Pg = P + (size_t)g * TAPS * NCHN;
    Pg[pb * NCHN + c] = make_float2(x0 * invT, y0 * invT);
    Pg[(pb + 1) * NCHN + c] = make_float2(x1 * invT, y1 * invT);
  }
}

// ---------------- LU solve with partial pivoting (complex128) ----------------
__global__ void solve_kernel(const float2* __restrict__ R, const float2* __restrict__ P,
                             float* __restrict__ gout, float2* __restrict__ gct) {
  __shared__ double2 A[TAPS][TAPS];
  __shared__ double2 Bm[TAPS][NCHN];
  __shared__ int piv;
  int g = blockIdx.x;
  int tid = threadIdx.x;
  int s = g & 1;
  int bf = g >> 1;
  int f = bf % NFREQ;
  int b = bf / NFREQ;
  int bs = b * NSPK + s;

  for (int i = tid; i < TAPS * TAPS; i += 64) {
    float2 r = R[(size_t)g * TAPS * TAPS + i];
    A[i / TAPS][i % TAPS] = make_double2((double)r.x, (double)r.y);
  }
  for (int i = tid; i < TAPS * NCHN; i += 64) {
    float2 p = P[(size_t)g * TAPS * NCHN + i];
    Bm[i / NCHN][i % NCHN] = make_double2((double)p.x, (double)p.y);
  }
  __syncthreads();
  if (tid < TAPS) A[tid][tid].x += LAMBDA_REG;
  __syncthreads();

  for (int k = 0; k < TAPS; ++k) {
    if (tid == 0) {
      int r = k;
      double best = fabs(A[k][k].x) + fabs(A[k][k].y);
      for (int i = k + 1; i < TAPS; ++i) {
        double v = fabs(A[i][k].x) + fabs(A[i][k].y);
        if (v > best) { best = v; r = i; }
      }
      piv = r;
    }
    __syncthreads();
    int r = piv;
    if (r != k) {
      if (tid < TAPS) {
        double2 tmp = A[k][tid]; A[k][tid] = A[r][tid]; A[r][tid] = tmp;
      } else if (tid < TAPS + NCHN) {
        int c = tid - TAPS;
        double2 tmp = Bm[k][c]; Bm[k][c] = Bm[r][c]; Bm[r][c] = tmp;
      }
    }
    __syncthreads();
    double2 akk = A[k][k];
    double den = akk.x * akk.x + akk.y * akk.y;
    if (tid > k && tid < TAPS) {
      double2 a = A[tid][k];
      A[tid][k] = make_double2((a.x * akk.x + a.y * akk.y) / den,
                               (a.y * akk.x - a.x * akk.y) / den);
    }
    __syncthreads();
    int nr = TAPS - 1 - k;
    int nc = nr + NCHN;
    for (int idx = tid; idx < nr * nc; idx += 64) {
      int i = k + 1 + idx / nc;
      int jj = idx % nc;
      double2 mlt = A[i][k];
      if (jj < nr) {
        int j = k + 1 + jj;
        double2 u = A[k][j];
        A[i][j].x -= mlt.x * u.x - mlt.y * u.y;
        A[i][j].y -= mlt.x * u.y + mlt.y * u.x;
      } else {
        int c = jj - nr;
        double2 u = Bm[k][c];
        Bm[i][c].x -= mlt.x * u.x - mlt.y * u.y;
        Bm[i][c].y -= mlt.x * u.y + mlt.y * u.x;
      }
    }
    __syncthreads();
  }

  if (tid < NCHN) {
    int c = tid;
    for (int k = TAPS - 1; k >= 0; --k) {
      double sx = Bm[k][c].x, sy = Bm[k][c].y;
      for (int j = k + 1; j < TAPS; ++j) {
        double2 u = A[k][j], xv = Bm[j][c];
        sx -= u.x * xv.x - u.y * xv.y;
        sy -= u.x * xv.y + u.y * xv.x;
      }
      double2 akk = A[k][k];
      double den = akk.x * akk.x + akk.y * akk.y;
      Bm[k][c] = make_double2((sx * akk.x + sy * akk.y) / den,
                              (sy * akk.x - sx * akk.y) / den);
    }
  }
  __syncthreads();

  for (int i = tid; i < TAPS * NCHN; i += 64) {
    int p = i / NCHN, c = i - p * NCHN;
    double2 gv = Bm[p][c];
    float gx = (float)gv.x, gy = (float)(-gv.y);  // conj(G)
    gout[(size_t)g * TAPS * NCHN + i] = gx;       // float32, real part only
    gct[(((size_t)bs * TAPS + p) * NCHN + c) * NFREQ + f] = make_float2(gx, gy);
  }
}

// ---------------- ret + inverse FFT (dual-frame, XCD-swizzled) ----------------
__global__ void ret_ifft_kernel(const float2* __restrict__ spht, const float2* __restrict__ gct,
                                float* __restrict__ frames) {
  __shared__ float2 buf[2 * NFFT];
  constexpr int NBLK = NSIG * NCH2;
  int bid = blockIdx.x;
  int blk = (bid & 7) * (NBLK / 8) + (bid >> 3);  // XCD-aware swizzle
  int ch = blk % NCH2;
  int sc = blk / NCH2;
  int t0 = ch * 2;
  bool dual = (t0 + 1 < NT);
  int c = sc % NCHN;
  int bs = sc / NCHN;
  int tid = threadIdx.x;

  const float2* gbase = gct + ((size_t)bs * TAPS * NCHN + c) * NFREQ;
  const float2* ysig = spht + (size_t)bs * NT * NFREQ;
  for (int f = tid; f < NFREQ; f += 256) {
    float sx0 = 0.0f, sy0 = 0.0f, sx1 = 0.0f, sy1 = 0.0f;
    float2 gprev = make_float2(0.0f, 0.0f);
#pragma unroll
    for (int k = 0; k <= TAPS; ++k) {  // k = p(frame0); p(frame1) = k-1
      int u = t0 - (TAPS - 1) + k;
      float2 y = (u >= 0 && u < NT) ? ysig[(size_t)u * NFREQ + f] : make_float2(0.0f, 0.0f);
      float2 gc = (k < TAPS) ? gbase[(size_t)k * NCHN * NFREQ + f] : make_float2(0.0f, 0.0f);
      if (k < TAPS) {
        sx0 += y.x * gc.x - y.y * gc.y;
        sy0 += y.x * gc.y + y.y * gc.x;
      }
      if (k >= 1) {
        sx1 += y.x * gprev.x - y.y * gprev.y;
        sy1 += y.x * gprev.y + y.y * gprev.x;
      }
      gprev = gc;
    }
    int r = rev9(f);
    buf[r] = make_float2(sx0, sy0);
    buf[NFFT + r] = make_float2(sx1, sy1);
    if (f > 0 && f < NFFT / 2) {
      int r2 = rev9(NFFT - f);
      buf[r2] = make_float2(sx0, -sy0);
      buf[NFFT + r2] = make_float2(sx1, -sy1);
    }
  }
  __syncthreads();
  fft512_dual(buf, tid, +1.0f);

  float* frow = frames + ((size_t)sc * NT + t0) * NFFT;
  for (int n = tid; n < NFFT; n += 256) {
    float w = __sinf(PI_F * (float)n / (float)NFFT);
    frow[n] = buf[n].x * (1.0f / (float)NFFT) * w;
    if (dual) frow[NFFT + n] = buf[NFFT + n].x * (1.0f / (float)NFFT) * w;
  }
}

// ---------------- overlap-add + env normalize + crop (float32 out) ----------------
__global__ void ola_kernel(const float* __restrict__ frames, float* __restrict__ out) {
  int i = blockIdx.x * 256 + threadIdx.x;
  if (i >= NSIG * LSIG) return;
  int sig = i / LSIG;
  int l = i - sig * LSIG;
  int lp = l + NFFT / 2;
  int j0 = max(0, (lp - (NFFT - HOPSZ)) / HOPSZ);
  int j1 = min(NT - 1, lp / HOPSZ);
  float acc = 0.0f;
  for (int j = j0; j <= j1; ++j) {
    int n = lp - j * HOPSZ;
    acc += frames[((size_t)sig * NT + j) * NFFT + n];
  }
  float env;
  if (j1 - j0 == 3) {
    env = 2.0f;  // sum sin^2(theta + k*pi/4), k=0..3 == 2 exactly
  } else {
    env = 0.0f;
    for (int j = j0; j <= j1; ++j) {
      int n = lp - j * HOPSZ;
      float w = __sinf(PI_F * (float)n / (float)NFFT);
      env += w * w;
    }
    if (env <= 1e-11f) env = 1.0f;
  }
  out[(size_t)G_ELEMS + i] = acc / env;
}

}  // namespace

extern "C" void kernel_launch(void* const* d_in, const int* in_sizes, int n_in,
                              void* d_out, int out_size, void* d_ws, size_t ws_size,
                              hipStream_t stream) {
  const float* ref = (const float*)d_in[0];
  const float* mix = (const float*)d_in[1];
  if (n_in >= 2 && in_sizes[0] > in_sizes[1]) {
    const float* tmp = ref; ref = mix; mix = tmp;
  }
  char* ws = (char*)d_ws;

  float2*  sph   = (float2*)(ws + SPH_B);
  float2*  spht  = (float2*)(ws + SPHT_B);
  float2*  mxs   = (float2*)(ws + MXS_B);
  float*   power = (float*)(ws + POW_B);
  float*   mx    = (float*)(ws + MX_B);
  float2*  R     = (float2*)(ws + R_B);
  float2*  P     = (float2*)(ws + P_B);
  float2*  gct   = (float2*)(ws + GCT_B);
  float*   frames= (float*)(ws + FRM_B);
  float*   out   = (float*)d_out;

  stft_kernel<<<dim3((NB * NSPK + NB * NCHN) * NCH2), dim3(256), 0, stream>>>(ref, mix, sph, spht, mxs);
  power_kernel<<<dim3((NB * NFREQ * NT + 255) / 256), dim3(256), 0, stream>>>(mxs, power);
  max_kernel<<<dim3(NB), dim3(256), 0, stream>>>(power, mx);
  rp_kernel<<<dim3(NG), dim3(256), 0, stream>>>(sph, mxs, power, mx, R, P);
  solve_kernel<<<dim3(NG), dim3(64), 0, stream>>>(R, P, out, gct);
  ret_ifft_kernel<<<dim3(NSIG * NCH2), dim3(256), 0, stream>>>(spht, gct, frames);
  ola_kernel<<<dim3((NSIG * LSIG + 255) / 256), dim3(256), 0, stream>>>(frames, out);
}

// Round 13
// 388.839 us; speedup vs baseline: 1.4497x; 1.0380x over previous
//
#include <hip/hip_runtime.h>
#include <math.h>

namespace {

constexpr int NB = 4, NSPK = 2, NCHN = 6;
constexpr int LSIG = 64000;
constexpr int NFFT = 512, HOPSZ = 128, NFREQ = 257;
constexpr int NT = 505;               // frames
constexpr int TAPS = 20;
constexpr int NG = NB * NFREQ * NSPK; // 2056 systems
constexpr int NSIG = NB * NSPK * NCHN; // 48 istft signals
constexpr float PI_F = 3.14159265358979323846f;
constexpr double LAMBDA_REG = 2e-4;
constexpr float FCP_EPS_F = 1e-3f;
constexpr int G_ELEMS = NG * TAPS * NCHN; // 246720 floats (real part only)
constexpr int NCH2 = (NT + 1) / 2;    // 253 two-frame chunks (last is single)
constexpr int YPAD_N = TAPS + 2 + NT; // 527: [0..18]=0, [19+u]=Y[u], tail zeros
constexpr int NR_TILES = 55;          // 2x2 tiles of lower triangle (10x10 tile grid)
constexpr int NP_THREADS = 60;        // 10 p-pairs x 6 channels
constexpr int THALF = 253;            // t split point (half0=[0,253), half1=[253,505))

constexpr size_t WS_ALIGN = 256;
constexpr size_t align_up(size_t x) { return (x + WS_ALIGN - 1) & ~(WS_ALIGN - 1); }

// ws byte offsets
constexpr size_t SPH_B  = 0;                                        // [8][257][505] float2
constexpr size_t SPH_SZ = (size_t)NB * NSPK * NFREQ * NT * 8;
constexpr size_t SPHT_B = align_up(SPH_B + SPH_SZ);                 // [8][505][257] float2
constexpr size_t MXS_B  = align_up(SPHT_B + SPH_SZ);                // [24][257][505] float2
constexpr size_t MXS_SZ = (size_t)NB * NCHN * NFREQ * NT * 8;
constexpr size_t POW_B  = align_up(MXS_B + MXS_SZ);                 // [4][257][505] float
constexpr size_t POW_SZ = (size_t)NB * NFREQ * NT * 4;
constexpr size_t MX_B   = align_up(POW_B + POW_SZ);                 // [4] float
constexpr size_t R_B    = align_up(MX_B + (size_t)NB * 4);          // [2056][400] float2
constexpr size_t R_SZ   = (size_t)NG * TAPS * TAPS * 8;
constexpr size_t P_B    = align_up(R_B + R_SZ);                     // [2056][120] float2
constexpr size_t P_SZ   = (size_t)NG * TAPS * NCHN * 8;
constexpr size_t GCT_B  = align_up(P_B + P_SZ);                     // [8][20][6][257] float2
constexpr size_t GCT_SZ = (size_t)NB * NSPK * TAPS * NCHN * NFREQ * 8;
constexpr size_t FRM_B  = align_up(GCT_B + GCT_SZ);                 // [48][505][512] float

__device__ __forceinline__ int rev9(int n) { return (int)(__brev((unsigned)n) >> 23); }

// Dual in-LDS radix-2 DIT FFT (two independent 512-pt transforms).
__device__ __forceinline__ void fft512_dual(float2* buf, int tid, float sign) {
#pragma unroll
  for (int s = 1; s <= 9; ++s) {
    int half = 1 << (s - 1);
    int blk = tid >> (s - 1);
    int pos = tid & (half - 1);
    int i0 = (blk << s) + pos;
    int i1 = i0 + half;
    float ang = sign * 2.0f * PI_F * (float)pos / (float)(half << 1);
    float sn, cs;
    __sincosf(ang, &sn, &cs);
    {
      float2 u = buf[i0], v = buf[i1];
      float2 vw = make_float2(v.x * cs - v.y * sn, v.x * sn + v.y * cs);
      buf[i0] = make_float2(u.x + vw.x, u.y + vw.y);
      buf[i1] = make_float2(u.x - vw.x, u.y - vw.y);
    }
    {
      float2 u = buf[NFFT + i0], v = buf[NFFT + i1];
      float2 vw = make_float2(v.x * cs - v.y * sn, v.x * sn + v.y * cs);
      buf[NFFT + i0] = make_float2(u.x + vw.x, u.y + vw.y);
      buf[NFFT + i1] = make_float2(u.x - vw.x, u.y - vw.y);
    }
    __syncthreads();
  }
}

// ---------------- STFT (dual-frame radix-2 FFT) ----------------
__global__ void stft_kernel(const float* __restrict__ ref, const float* __restrict__ mix,
                            float2* __restrict__ sph, float2* __restrict__ spht,
                            float2* __restrict__ mxs) {
  __shared__ float2 buf[2 * NFFT];
  int blk = blockIdx.x;
  int sig = blk / NCH2;
  int ch = blk - sig * NCH2;
  int t0 = ch * 2;
  bool dual = (t0 + 1 < NT);
  int tid = threadIdx.x;
  bool is_ref = sig < NB * NSPK;
  int m = is_ref ? sig : (sig - NB * NSPK);
  const float* src = is_ref ? (ref + (size_t)m * LSIG) : (mix + (size_t)m * LSIG);

  for (int n = tid; n < NFFT; n += 256) {
    float w = __sinf(PI_F * (float)n / (float)NFFT);  // sqrt-hann
    int g0 = t0 * HOPSZ + n - NFFT / 2;
    float v0 = (g0 >= 0 && g0 < LSIG) ? src[g0] : 0.0f;
    int g1 = g0 + HOPSZ;
    float v1 = (dual && g1 >= 0 && g1 < LSIG) ? src[g1] : 0.0f;
    int r = rev9(n);
    buf[r] = make_float2(v0 * w, 0.0f);
    buf[NFFT + r] = make_float2(v1 * w, 0.0f);
  }
  __syncthreads();
  fft512_dual(buf, tid, -1.0f);

  if (is_ref) {
    float2* d1 = sph + (size_t)m * NFREQ * NT;
    float2* d2 = spht + ((size_t)m * NT + t0) * NFREQ;
    for (int f = tid; f < NFREQ; f += 256) {
      float2 v0 = buf[f], v1 = buf[NFFT + f];
      d1[(size_t)f * NT + t0] = v0;
      d2[f] = v0;
      if (dual) {
        d1[(size_t)f * NT + t0 + 1] = v1;
        d2[NFREQ + f] = v1;
      }
    }
  } else {
    float2* d1 = mxs + (size_t)m * NFREQ * NT;
    for (int f = tid; f < NFREQ; f += 256) {
      d1[(size_t)f * NT + t0] = buf[f];
      if (dual) d1[(size_t)f * NT + t0 + 1] = buf[NFFT + f];
    }
  }
}

// ---------------- power ----------------
__global__ void power_kernel(const float2* __restrict__ mxs, float* __restrict__ power) {
  int i = blockIdx.x * 256 + threadIdx.x;
  if (i >= NB * NFREQ * NT) return;
  int b = i / (NFREQ * NT);
  int r = i - b * (NFREQ * NT);
  float acc = 0.0f;
#pragma unroll
  for (int c = 0; c < NCHN; ++c) {
    float2 v = mxs[(size_t)(b * NCHN + c) * NFREQ * NT + r];
    acc += v.x * v.x + v.y * v.y;
  }
  power[i] = acc * (1.0f / (float)NCHN);
}

// ---------------- per-batch max ----------------
__global__ void max_kernel(const float* __restrict__ power, float* __restrict__ mx) {
  int b = blockIdx.x;
  const float* p = power + (size_t)b * NFREQ * NT;
  float m = 0.0f;
  for (int i = threadIdx.x; i < NFREQ * NT; i += 256) m = fmaxf(m, p[i]);
#pragma unroll
  for (int off = 32; off > 0; off >>= 1) m = fmaxf(m, __shfl_down(m, off, 64));
  __shared__ float sm[4];
  int wave = threadIdx.x >> 6, lane = threadIdx.x & 63;
  if (lane == 0) sm[wave] = m;
  __syncthreads();
  if (threadIdx.x == 0) mx[b] = fmaxf(fmaxf(sm[0], sm[1]), fmaxf(sm[2], sm[3]));
}

// ---------------- R / P accumulation (register-tiled, t-split across waves) ----------------
// 256 threads, 4 waves ALL active in the main loop:
//   wave0: R 2x2 tiles, t in [0,253)     wave1: R tiles, t in [253,505)
//   wave2: P 2x1 tiles, t in [0,253)     wave3: P tiles, t in [253,505)
// Half-1 waves dump partials into LDS (reusing dead Ypad space); half-0 adds+stores.
__global__ void rp_kernel(const float2* __restrict__ sph, const float2* __restrict__ mxs,
                          const float* __restrict__ power, const float* __restrict__ mx,
                          float2* __restrict__ R, float2* __restrict__ P) {
  __shared__ float2 Ypad[YPAD_N];      // [0..18]=0, [19+u]=Y[u], tail zeros
  __shared__ float2 MWsh[NCHN][NT];    // w[t] * conj(M[c][t])
  __shared__ float Wsh[NT];
  int g = blockIdx.x;
  int s = g & 1;
  int bf = g >> 1;
  int f = bf % NFREQ;
  int b = bf / NFREQ;
  int tid = threadIdx.x;

  const float2* yrow = sph + ((size_t)(b * NSPK + s) * NFREQ + f) * NT;
  const float* prow = power + ((size_t)b * NFREQ + f) * NT;
  float add = mx[b] * FCP_EPS_F + 1e-6f;
  for (int t = tid; t < NT; t += 256) Wsh[t] = 1.0f / (prow[t] + add);
  for (int i = tid; i < YPAD_N; i += 256) {
    bool in = (i >= TAPS - 1) && (i < TAPS - 1 + NT);
    Ypad[i] = in ? yrow[i - (TAPS - 1)] : make_float2(0.0f, 0.0f);
  }
  __syncthreads();
  for (int i = tid; i < NCHN * NT; i += 256) {
    int c = i / NT, t = i - c * NT;
    float2 m = mxs[((size_t)(b * NCHN + c) * NFREQ + f) * NT + t];
    float w = Wsh[t];
    MWsh[c][t] = make_float2(w * m.x, -w * m.y);
  }
  __syncthreads();

  const float invT = 1.0f / (float)NT;
  int wave = tid >> 6;
  int lane = tid & 63;
  float* scratch = (float*)Ypad;  // dead after accumulation; 680 floats used

  if ((wave == 0 || wave == 1) && lane < NR_TILES) {
    int half = wave;
    int tlo = half ? THALF : 0;
    int thi = half ? NT : THALF;
    // tile (I,J), I>=J: rows p=2I,2I+1; cols q=2J,2J+1
    int I = (int)((sqrtf(8.0f * (float)lane + 1.0f) - 1.0f) * 0.5f);
    while ((I + 1) * (I + 2) / 2 <= lane) ++I;
    while (I * (I + 1) / 2 > lane) --I;
    int J = lane - I * (I + 1) / 2;
    int pb = 2 * I, qb = 2 * J;
    float2 a0 = Ypad[pb + tlo], a1 = Ypad[pb + tlo + 1];
    float2 b0 = Ypad[qb + tlo], b1 = Ypad[qb + tlo + 1];
    float x00 = 0.f, y00 = 0.f, x01 = 0.f, y01 = 0.f;
    float x10 = 0.f, y10 = 0.f, x11 = 0.f, y11 = 0.f;
    for (int t = tlo; t < thi; ++t) {
      float w = Wsh[t];
      x00 = fmaf(w, a0.x * b0.x + a0.y * b0.y, x00);
      y00 = fmaf(w, a0.y * b0.x - a0.x * b0.y, y00);
      x01 = fmaf(w, a0.x * b1.x + a0.y * b1.y, x01);
      y01 = fmaf(w, a0.y * b1.x - a0.x * b1.y, y01);
      x10 = fmaf(w, a1.x * b0.x + a1.y * b0.y, x10);
      y10 = fmaf(w, a1.y * b0.x - a1.x * b0.y, y10);
      x11 = fmaf(w, a1.x * b1.x + a1.y * b1.y, x11);
      y11 = fmaf(w, a1.y * b1.x - a1.x * b1.y, y11);
      a0 = a1; a1 = Ypad[pb + 2 + t];   // slide window
      b0 = b1; b1 = Ypad[qb + 2 + t];
    }
    __syncthreads();                     // Ypad reads done block-wide
    if (half == 1) {
      float* d = scratch + lane * 8;
      d[0] = x00; d[1] = y00; d[2] = x01; d[3] = y01;
      d[4] = x10; d[5] = y10; d[6] = x11; d[7] = y11;
    }
    __syncthreads();
    if (half == 0) {
      const float* d = scratch + lane * 8;
      x00 += d[0]; y00 += d[1]; x01 += d[2]; y01 += d[3];
      x10 += d[4]; y10 += d[5]; x11 += d[6]; y11 += d[7];
      float2* Rg = R + (size_t)g * TAPS * TAPS;
#define STORE_R(p_, q_, xx, yy)                                       \
      if ((p_) >= (q_)) {                                              \
        float rx = (xx) * invT, ry = (yy) * invT;                      \
        Rg[(p_) * TAPS + (q_)] = make_float2(rx, ry);                  \
        if ((p_) != (q_)) Rg[(q_) * TAPS + (p_)] = make_float2(rx, -ry); \
      }
      STORE_R(pb, qb, x00, y00)
      STORE_R(pb, qb + 1, x01, y01)
      STORE_R(pb + 1, qb, x10, y10)
      STORE_R(pb + 1, qb + 1, x11, y11)
#undef STORE_R
    }
  } else if ((wave == 2 || wave == 3) && lane < NP_THREADS) {
    int half = wave - 2;
    int tlo = half ? THALF : 0;
    int thi = half ? NT : THALF;
    int ih = lane / NCHN, c = lane - ih * NCHN;
    int pb = 2 * ih;
    float2 a0 = Ypad[pb + tlo], a1 = Ypad[pb + tlo + 1];
    float x0 = 0.f, y0 = 0.f, x1 = 0.f, y1 = 0.f;
    const float2* MW = &MWsh[c][0];
    for (int t = tlo; t < thi; ++t) {
      float2 mw = MW[t];
      x0 += a0.x * mw.x - a0.y * mw.y;
      y0 += a0.x * mw.y + a0.y * mw.x;
      x1 += a1.x * mw.x - a1.y * mw.y;
      y1 += a1.x * mw.y + a1.y * mw.x;
      a0 = a1; a1 = Ypad[pb + 2 + t];
    }
    __syncthreads();
    if (half == 1) {
      float* d = scratch + NR_TILES * 8 + lane * 4;
      d[0] = x0; d[1] = y0; d[2] = x1; d[3] = y1;
    }
    __syncthreads();
    if (half == 0) {
      const float* d = scratch + NR_TILES * 8 + lane * 4;
      x0 += d[0]; y0 += d[1]; x1 += d[2]; y1 += d[3];
      float2* Pg = P + (size_t)g * TAPS * NCHN;
      Pg[pb * NCHN + c] = make_float2(x0 * invT, y0 * invT);
      Pg[(pb + 1) * NCHN + c] = make_float2(x1 * invT, y1 * invT);
    }
  } else {
    __syncthreads();   // keep barriers block-uniform
    __syncthreads();
  }
}

// ---------------- LU solve with partial pivoting (complex128) ----------------
__global__ void solve_kernel(const float2* __restrict__ R, const float2* __restrict__ P,
                             float* __restrict__ gout, float2* __restrict__ gct) {
  __shared__ double2 A[TAPS][TAPS];
  __shared__ double2 Bm[TAPS][NCHN];
  __shared__ int piv;
  int g = blockIdx.x;
  int tid = threadIdx.x;
  int s = g & 1;
  int bf = g >> 1;
  int f = bf % NFREQ;
  int b = bf / NFREQ;
  int bs = b * NSPK + s;

  for (int i = tid; i < TAPS * TAPS; i += 64) {
    float2 r = R[(size_t)g * TAPS * TAPS + i];
    A[i / TAPS][i % TAPS] = make_double2((double)r.x, (double)r.y);
  }
  for (int i = tid; i < TAPS * NCHN; i += 64) {
    float2 p = P[(size_t)g * TAPS * NCHN + i];
    Bm[i / NCHN][i % NCHN] = make_double2((double)p.x, (double)p.y);
  }
  __syncthreads();
  if (tid < TAPS) A[tid][tid].x += LAMBDA_REG;
  __syncthreads();

  for (int k = 0; k < TAPS; ++k) {
    if (tid == 0) {
      int r = k;
      double best = fabs(A[k][k].x) + fabs(A[k][k].y);
      for (int i = k + 1; i < TAPS; ++i) {
        double v = fabs(A[i][k].x) + fabs(A[i][k].y);
        if (v > best) { best = v; r = i; }
      }
      piv = r;
    }
    __syncthreads();
    int r = piv;
    if (r != k) {
      if (tid < TAPS) {
        double2 tmp = A[k][tid]; A[k][tid] = A[r][tid]; A[r][tid] = tmp;
      } else if (tid < TAPS + NCHN) {
        int c = tid - TAPS;
        double2 tmp = Bm[k][c]; Bm[k][c] = Bm[r][c]; Bm[r][c] = tmp;
      }
    }
    __syncthreads();
    double2 akk = A[k][k];
    double den = akk.x * akk.x + akk.y * akk.y;
    if (tid > k && tid < TAPS) {
      double2 a = A[tid][k];
      A[tid][k] = make_double2((a.x * akk.x + a.y * akk.y) / den,
                               (a.y * akk.x - a.x * akk.y) / den);
    }
    __syncthreads();
    int nr = TAPS - 1 - k;
    int nc = nr + NCHN;
    for (int idx = tid; idx < nr * nc; idx += 64) {
      int i = k + 1 + idx / nc;
      int jj = idx % nc;
      double2 mlt = A[i][k];
      if (jj < nr) {
        int j = k + 1 + jj;
        double2 u = A[k][j];
        A[i][j].x -= mlt.x * u.x - mlt.y * u.y;
        A[i][j].y -= mlt.x * u.y + mlt.y * u.x;
      } else {
        int c = jj - nr;
        double2 u = Bm[k][c];
        Bm[i][c].x -= mlt.x * u.x - mlt.y * u.y;
        Bm[i][c].y -= mlt.x * u.y + mlt.y * u.x;
      }
    }
    __syncthreads();
  }

  if (tid < NCHN) {
    int c = tid;
    for (int k = TAPS - 1; k >= 0; --k) {
      double sx = Bm[k][c].x, sy = Bm[k][c].y;
      for (int j = k + 1; j < TAPS; ++j) {
        double2 u = A[k][j], xv = Bm[j][c];
        sx -= u.x * xv.x - u.y * xv.y;
        sy -= u.x * xv.y + u.y * xv.x;
      }
      double2 akk = A[k][k];
      double den = akk.x * akk.x + akk.y * akk.y;
      Bm[k][c] = make_double2((sx * akk.x + sy * akk.y) / den,
                              (sy * akk.x - sx * akk.y) / den);
    }
  }
  __syncthreads();

  for (int i = tid; i < TAPS * NCHN; i += 64) {
    int p = i / NCHN, c = i - p * NCHN;
    double2 gv = Bm[p][c];
    float gx = (float)gv.x, gy = (float)(-gv.y);  // conj(G)
    gout[(size_t)g * TAPS * NCHN + i] = gx;       // float32, real part only
    gct[(((size_t)bs * TAPS + p) * NCHN + c) * NFREQ + f] = make_float2(gx, gy);
  }
}

// ---------------- ret + inverse FFT (dual-frame, XCD-swizzled) ----------------
__global__ void ret_ifft_kernel(const float2* __restrict__ spht, const float2* __restrict__ gct,
                                float* __restrict__ frames) {
  __shared__ float2 buf[2 * NFFT];
  constexpr int NBLK = NSIG * NCH2;
  int bid = blockIdx.x;
  int blk = (bid & 7) * (NBLK / 8) + (bid >> 3);  // XCD-aware swizzle
  int ch = blk % NCH2;
  int sc = blk / NCH2;
  int t0 = ch * 2;
  bool dual = (t0 + 1 < NT);
  int c = sc % NCHN;
  int bs = sc / NCHN;
  int tid = threadIdx.x;

  const float2* gbase = gct + ((size_t)bs * TAPS * NCHN + c) * NFREQ;
  const float2* ysig = spht + (size_t)bs * NT * NFREQ;
  for (int f = tid; f < NFREQ; f += 256) {
    float sx0 = 0.0f, sy0 = 0.0f, sx1 = 0.0f, sy1 = 0.0f;
    float2 gprev = make_float2(0.0f, 0.0f);
#pragma unroll
    for (int k = 0; k <= TAPS; ++k) {  // k = p(frame0); p(frame1) = k-1
      int u = t0 - (TAPS - 1) + k;
      float2 y = (u >= 0 && u < NT) ? ysig[(size_t)u * NFREQ + f] : make_float2(0.0f, 0.0f);
      float2 gc = (k < TAPS) ? gbase[(size_t)k * NCHN * NFREQ + f] : make_float2(0.0f, 0.0f);
      if (k < TAPS) {
        sx0 += y.x * gc.x - y.y * gc.y;
        sy0 += y.x * gc.y + y.y * gc.x;
      }
      if (k >= 1) {
        sx1 += y.x * gprev.x - y.y * gprev.y;
        sy1 += y.x * gprev.y + y.y * gprev.x;
      }
      gprev = gc;
    }
    int r = rev9(f);
    buf[r] = make_float2(sx0, sy0);
    buf[NFFT + r] = make_float2(sx1, sy1);
    if (f > 0 && f < NFFT / 2) {
      int r2 = rev9(NFFT - f);
      buf[r2] = make_float2(sx0, -sy0);
      buf[NFFT + r2] = make_float2(sx1, -sy1);
    }
  }
  __syncthreads();
  fft512_dual(buf, tid, +1.0f);

  float* frow = frames + ((size_t)sc * NT + t0) * NFFT;
  for (int n = tid; n < NFFT; n += 256) {
    float w = __sinf(PI_F * (float)n / (float)NFFT);
    frow[n] = buf[n].x * (1.0f / (float)NFFT) * w;
    if (dual) frow[NFFT + n] = buf[NFFT + n].x * (1.0f / (float)NFFT) * w;
  }
}

// ---------------- overlap-add + env normalize + crop (float32 out) ----------------
__global__ void ola_kernel(const float* __restrict__ frames, float* __restrict__ out) {
  int i = blockIdx.x * 256 + threadIdx.x;
  if (i >= NSIG * LSIG) return;
  int sig = i / LSIG;
  int l = i - sig * LSIG;
  int lp = l + NFFT / 2;
  int j0 = max(0, (lp - (NFFT - HOPSZ)) / HOPSZ);
  int j1 = min(NT - 1, lp / HOPSZ);
  float acc = 0.0f;
  for (int j = j0; j <= j1; ++j) {
    int n = lp - j * HOPSZ;
    acc += frames[((size_t)sig * NT + j) * NFFT + n];
  }
  float env;
  if (j1 - j0 == 3) {
    env = 2.0f;  // sum sin^2(theta + k*pi/4), k=0..3 == 2 exactly
  } else {
    env = 0.0f;
    for (int j = j0; j <= j1; ++j) {
      int n = lp - j * HOPSZ;
      float w = __sinf(PI_F * (float)n / (float)NFFT);
      env += w * w;
    }
    if (env <= 1e-11f) env = 1.0f;
  }
  out[(size_t)G_ELEMS + i] = acc / env;
}

}  // namespace

extern "C" void kernel_launch(void* const* d_in, const int* in_sizes, int n_in,
                              void* d_out, int out_size, void* d_ws, size_t ws_size,
                              hipStream_t stream) {
  const float* ref = (const float*)d_in[0];
  const float* mix = (const float*)d_in[1];
  if (n_in >= 2 && in_sizes[0] > in_sizes[1]) {
    const float* tmp = ref; ref = mix; mix = tmp;
  }
  char* ws = (char*)d_ws;

  float2*  sph   = (float2*)(ws + SPH_B);
  float2*  spht  = (float2*)(ws + SPHT_B);
  float2*  mxs   = (float2*)(ws + MXS_B);
  float*   power = (float*)(ws + POW_B);
  float*   mx    = (float*)(ws + MX_B);
  float2*  R     = (float2*)(ws + R_B);
  float2*  P     = (float2*)(ws + P_B);
  float2*  gct   = (float2*)(ws + GCT_B);
  float*   frames= (float*)(ws + FRM_B);
  float*   out   = (float*)d_out;

  stft_kernel<<<dim3((NB * NSPK + NB * NCHN) * NCH2), dim3(256), 0, stream>>>(ref, mix, sph, spht, mxs);
  power_kernel<<<dim3((NB * NFREQ * NT + 255) / 256), dim3(256), 0, stream>>>(mxs, power);
  max_kernel<<<dim3(NB), dim3(256), 0, stream>>>(power, mx);
  rp_kernel<<<dim3(NG), dim3(256), 0, stream>>>(sph, mxs, power, mx, R, P);
  solve_kernel<<<dim3(NG), dim3(64), 0, stream>>>(R, P, out, gct);
  ret_ifft_kernel<<<dim3(NSIG * NCH2), dim3(256), 0, stream>>>(spht, gct, frames);
  ola_kernel<<<dim3((NSIG * LSIG + 255) / 256), dim3(256), 0, stream>>>(frames, out);
}

// Round 14
// 380.017 us; speedup vs baseline: 1.4834x; 1.0232x over previous
//
#include <hip/hip_runtime.h>
#include <math.h>

namespace {

constexpr int NB = 4, NSPK = 2, NCHN = 6;
constexpr int LSIG = 64000;
constexpr int NFFT = 512, HOPSZ = 128, NFREQ = 257;
constexpr int NT = 505;               // frames
constexpr int TAPS = 20;
constexpr int NG = NB * NFREQ * NSPK; // 2056 systems
constexpr int NSIG = NB * NSPK * NCHN; // 48 istft signals
constexpr float PI_F = 3.14159265358979323846f;
constexpr double LAMBDA_REG = 2e-4;
constexpr float FCP_EPS_F = 1e-3f;
constexpr int G_ELEMS = NG * TAPS * NCHN; // 246720 floats (real part only)
constexpr int NCH2 = (NT + 1) / 2;    // 253 two-frame chunks (last is single)
constexpr int YPAD_N = TAPS + 2 + NT; // 527: [0..18]=0, [19+u]=Y[u], tail zeros
constexpr int NR_TILES = 55;          // 2x2 tiles of lower triangle (10x10 tile grid)
constexpr int NP_THREADS = 60;        // 10 p-pairs x 6 channels

constexpr size_t WS_ALIGN = 256;
constexpr size_t align_up(size_t x) { return (x + WS_ALIGN - 1) & ~(WS_ALIGN - 1); }

// ws byte offsets
constexpr size_t SPH_B  = 0;                                        // [8][257][505] float2
constexpr size_t SPH_SZ = (size_t)NB * NSPK * NFREQ * NT * 8;
constexpr size_t SPHT_B = align_up(SPH_B + SPH_SZ);                 // [8][505][257] float2
constexpr size_t MXS_B  = align_up(SPHT_B + SPH_SZ);                // [24][257][505] float2
constexpr size_t MXS_SZ = (size_t)NB * NCHN * NFREQ * NT * 8;
constexpr size_t POW_B  = align_up(MXS_B + MXS_SZ);                 // [4][257][505] float
constexpr size_t POW_SZ = (size_t)NB * NFREQ * NT * 4;
constexpr size_t MX_B   = align_up(POW_B + POW_SZ);                 // [4] float
constexpr size_t R_B    = align_up(MX_B + (size_t)NB * 4);          // [2056][400] float2
constexpr size_t R_SZ   = (size_t)NG * TAPS * TAPS * 8;
constexpr size_t P_B    = align_up(R_B + R_SZ);                     // [2056][120] float2
constexpr size_t P_SZ   = (size_t)NG * TAPS * NCHN * 8;
constexpr size_t GCT_B  = align_up(P_B + P_SZ);                     // [8][20][6][257] float2
constexpr size_t GCT_SZ = (size_t)NB * NSPK * TAPS * NCHN * NFREQ * 8;
constexpr size_t FRM_B  = align_up(GCT_B + GCT_SZ);                 // [48][505][512] float

__device__ __forceinline__ int rev9(int n) { return (int)(__brev((unsigned)n) >> 23); }

// Dual in-LDS radix-2 DIT FFT (two independent 512-pt transforms).
__device__ __forceinline__ void fft512_dual(float2* buf, int tid, float sign) {
#pragma unroll
  for (int s = 1; s <= 9; ++s) {
    int half = 1 << (s - 1);
    int blk = tid >> (s - 1);
    int pos = tid & (half - 1);
    int i0 = (blk << s) + pos;
    int i1 = i0 + half;
    float ang = sign * 2.0f * PI_F * (float)pos / (float)(half << 1);
    float sn, cs;
    __sincosf(ang, &sn, &cs);
    {
      float2 u = buf[i0], v = buf[i1];
      float2 vw = make_float2(v.x * cs - v.y * sn, v.x * sn + v.y * cs);
      buf[i0] = make_float2(u.x + vw.x, u.y + vw.y);
      buf[i1] = make_float2(u.x - vw.x, u.y - vw.y);
    }
    {
      float2 u = buf[NFFT + i0], v = buf[NFFT + i1];
      float2 vw = make_float2(v.x * cs - v.y * sn, v.x * sn + v.y * cs);
      buf[NFFT + i0] = make_float2(u.x + vw.x, u.y + vw.y);
      buf[NFFT + i1] = make_float2(u.x - vw.x, u.y - vw.y);
    }
    __syncthreads();
  }
}

// ---------------- STFT (dual-frame radix-2 FFT) ----------------
__global__ void stft_kernel(const float* __restrict__ ref, const float* __restrict__ mix,
                            float2* __restrict__ sph, float2* __restrict__ spht,
                            float2* __restrict__ mxs) {
  __shared__ float2 buf[2 * NFFT];
  int blk = blockIdx.x;
  int sig = blk / NCH2;
  int ch = blk - sig * NCH2;
  int t0 = ch * 2;
  bool dual = (t0 + 1 < NT);
  int tid = threadIdx.x;
  bool is_ref = sig < NB * NSPK;
  int m = is_ref ? sig : (sig - NB * NSPK);
  const float* src = is_ref ? (ref + (size_t)m * LSIG) : (mix + (size_t)m * LSIG);

  for (int n = tid; n < NFFT; n += 256) {
    float w = __sinf(PI_F * (float)n / (float)NFFT);  // sqrt-hann
    int g0 = t0 * HOPSZ + n - NFFT / 2;
    float v0 = (g0 >= 0 && g0 < LSIG) ? src[g0] : 0.0f;
    int g1 = g0 + HOPSZ;
    float v1 = (dual && g1 >= 0 && g1 < LSIG) ? src[g1] : 0.0f;
    int r = rev9(n);
    buf[r] = make_float2(v0 * w, 0.0f);
    buf[NFFT + r] = make_float2(v1 * w, 0.0f);
  }
  __syncthreads();
  fft512_dual(buf, tid, -1.0f);

  if (is_ref) {
    float2* d1 = sph + (size_t)m * NFREQ * NT;
    float2* d2 = spht + ((size_t)m * NT + t0) * NFREQ;
    for (int f = tid; f < NFREQ; f += 256) {
      float2 v0 = buf[f], v1 = buf[NFFT + f];
      d1[(size_t)f * NT + t0] = v0;
      d2[f] = v0;
      if (dual) {
        d1[(size_t)f * NT + t0 + 1] = v1;
        d2[NFREQ + f] = v1;
      }
    }
  } else {
    float2* d1 = mxs + (size_t)m * NFREQ * NT;
    for (int f = tid; f < NFREQ; f += 256) {
      d1[(size_t)f * NT + t0] = buf[f];
      if (dual) d1[(size_t)f * NT + t0 + 1] = buf[NFFT + f];
    }
  }
}

// ---------------- power ----------------
__global__ void power_kernel(const float2* __restrict__ mxs, float* __restrict__ power) {
  int i = blockIdx.x * 256 + threadIdx.x;
  if (i >= NB * NFREQ * NT) return;
  int b = i / (NFREQ * NT);
  int r = i - b * (NFREQ * NT);
  float acc = 0.0f;
#pragma unroll
  for (int c = 0; c < NCHN; ++c) {
    float2 v = mxs[(size_t)(b * NCHN + c) * NFREQ * NT + r];
    acc += v.x * v.x + v.y * v.y;
  }
  power[i] = acc * (1.0f / (float)NCHN);
}

// ---------------- per-batch max ----------------
__global__ void max_kernel(const float* __restrict__ power, float* __restrict__ mx) {
  int b = blockIdx.x;
  const float* p = power + (size_t)b * NFREQ * NT;
  float m = 0.0f;
  for (int i = threadIdx.x; i < NFREQ * NT; i += 256) m = fmaxf(m, p[i]);
#pragma unroll
  for (int off = 32; off > 0; off >>= 1) m = fmaxf(m, __shfl_down(m, off, 64));
  __shared__ float sm[4];
  int wave = threadIdx.x >> 6, lane = threadIdx.x & 63;
  if (lane == 0) sm[wave] = m;
  __syncthreads();
  if (threadIdx.x == 0) mx[b] = fmaxf(fmaxf(sm[0], sm[1]), fmaxf(sm[2], sm[3]));
}

// ---------------- R / P accumulation (register-tiled, 4-way t-split, 512 thr) ----------------
// 8 waves: waves 0-3 = R 2x2 tiles over t-quarters; waves 4-7 = P 2x1 tiles.
// Cross-wave reduction through LDS scratch (reuses dead MWsh region).
__global__ void rp_kernel(const float2* __restrict__ sph, const float2* __restrict__ mxs,
                          const float* __restrict__ power, const float* __restrict__ mx,
                          float2* __restrict__ R, float2* __restrict__ P) {
  __shared__ float2 Ypad[YPAD_N];      // [0..18]=0, [19+u]=Y[u], tail zeros
  __shared__ float2 MWsh[NCHN][NT];    // w[t] * conj(M[c][t]); scratch after loops
  __shared__ float Wsh[NT];
  int g = blockIdx.x;
  int s = g & 1;
  int bf = g >> 1;
  int f = bf % NFREQ;
  int b = bf / NFREQ;
  int tid = threadIdx.x;

  const float2* yrow = sph + ((size_t)(b * NSPK + s) * NFREQ + f) * NT;
  const float* prow = power + ((size_t)b * NFREQ + f) * NT;
  float add = mx[b] * FCP_EPS_F + 1e-6f;
  for (int t = tid; t < NT; t += 512) Wsh[t] = 1.0f / (prow[t] + add);
  for (int i = tid; i < YPAD_N; i += 512) {
    bool in = (i >= TAPS - 1) && (i < TAPS - 1 + NT);
    Ypad[i] = in ? yrow[i - (TAPS - 1)] : make_float2(0.0f, 0.0f);
  }
  __syncthreads();
  for (int i = tid; i < NCHN * NT; i += 512) {
    int c = i / NT, t = i - c * NT;
    float2 m = mxs[((size_t)(b * NCHN + c) * NFREQ + f) * NT + t];
    float w = Wsh[t];
    MWsh[c][t] = make_float2(w * m.x, -w * m.y);
  }
  __syncthreads();

  const float invT = 1.0f / (float)NT;
  const int TQ[5] = {0, 126, 252, 378, NT};
  int wave = tid >> 6;
  int lane = tid & 63;
  bool isR = (wave < 4) && (lane < NR_TILES);
  bool isP = (wave >= 4) && (lane < NP_THREADS);

  float x00 = 0.f, y00 = 0.f, x01 = 0.f, y01 = 0.f;
  float x10 = 0.f, y10 = 0.f, x11 = 0.f, y11 = 0.f;
  int pb = 0, qb = 0, pc = 0;

  if (isR) {
    int seg = wave;
    int tlo = TQ[seg], thi = TQ[seg + 1];
    int I = (int)((sqrtf(8.0f * (float)lane + 1.0f) - 1.0f) * 0.5f);
    while ((I + 1) * (I + 2) / 2 <= lane) ++I;
    while (I * (I + 1) / 2 > lane) --I;
    int J = lane - I * (I + 1) / 2;
    pb = 2 * I; qb = 2 * J;
    float2 a0 = Ypad[pb + tlo], a1 = Ypad[pb + tlo + 1];
    float2 b0 = Ypad[qb + tlo], b1 = Ypad[qb + tlo + 1];
    for (int t = tlo; t < thi; ++t) {
      float w = Wsh[t];
      x00 = fmaf(w, a0.x * b0.x + a0.y * b0.y, x00);
      y00 = fmaf(w, a0.y * b0.x - a0.x * b0.y, y00);
      x01 = fmaf(w, a0.x * b1.x + a0.y * b1.y, x01);
      y01 = fmaf(w, a0.y * b1.x - a0.x * b1.y, y01);
      x10 = fmaf(w, a1.x * b0.x + a1.y * b0.y, x10);
      y10 = fmaf(w, a1.y * b0.x - a1.x * b0.y, y10);
      x11 = fmaf(w, a1.x * b1.x + a1.y * b1.y, x11);
      y11 = fmaf(w, a1.y * b1.x - a1.x * b1.y, y11);
      a0 = a1; a1 = Ypad[pb + 2 + t];   // slide window
      b0 = b1; b1 = Ypad[qb + 2 + t];
    }
  } else if (isP) {
    int seg = wave - 4;
    int tlo = TQ[seg], thi = TQ[seg + 1];
    int ih = lane / NCHN;
    pc = lane - ih * NCHN;
    pb = 2 * ih;
    float2 a0 = Ypad[pb + tlo], a1 = Ypad[pb + tlo + 1];
    const float2* MW = &MWsh[pc][0];
    for (int t = tlo; t < thi; ++t) {
      float2 mw = MW[t];
      x00 += a0.x * mw.x - a0.y * mw.y;
      y00 += a0.x * mw.y + a0.y * mw.x;
      x10 += a1.x * mw.x - a1.y * mw.y;
      y10 += a1.x * mw.y + a1.y * mw.x;
      a0 = a1; a1 = Ypad[pb + 2 + t];
    }
  }
  __syncthreads();    // all loop reads (Ypad, MWsh, Wsh) complete

  float* scratch = (float*)MWsh;  // dead now; need 2040 floats of 24240
  if (isR && wave >= 1) {
    float* d = scratch + ((wave - 1) * NR_TILES + lane) * 8;
    d[0] = x00; d[1] = y00; d[2] = x01; d[3] = y01;
    d[4] = x10; d[5] = y10; d[6] = x11; d[7] = y11;
  }
  if (isP && wave >= 5) {
    float* d = scratch + 3 * NR_TILES * 8 + ((wave - 5) * NP_THREADS + lane) * 4;
    d[0] = x00; d[1] = y00; d[2] = x10; d[3] = y10;
  }
  __syncthreads();

  if (isR && wave == 0) {
#pragma unroll
    for (int sgi = 0; sgi < 3; ++sgi) {
      const float* d = scratch + (sgi * NR_TILES + lane) * 8;
      x00 += d[0]; y00 += d[1]; x01 += d[2]; y01 += d[3];
      x10 += d[4]; y10 += d[5]; x11 += d[6]; y11 += d[7];
    }
    float2* Rg = R + (size_t)g * TAPS * TAPS;
#define STORE_R(p_, q_, xx, yy)                                       \
    if ((p_) >= (q_)) {                                                \
      float rx = (xx) * invT, ry = (yy) * invT;                        \
      Rg[(p_) * TAPS + (q_)] = make_float2(rx, ry);                    \
      if ((p_) != (q_)) Rg[(q_) * TAPS + (p_)] = make_float2(rx, -ry); \
    }
    STORE_R(pb, qb, x00, y00)
    STORE_R(pb, qb + 1, x01, y01)
    STORE_R(pb + 1, qb, x10, y10)
    STORE_R(pb + 1, qb + 1, x11, y11)
#undef STORE_R
  }
  if (isP && wave == 4) {
#pragma unroll
    for (int sgi = 0; sgi < 3; ++sgi) {
      const float* d = scratch + 3 * NR_TILES * 8 + (sgi * NP_THREADS + lane) * 4;
      x00 += d[0]; y00 += d[1]; x10 += d[2]; y10 += d[3];
    }
    float2* Pg = P + (size_t)g * TAPS * NCHN;
    Pg[pb * NCHN + pc] = make_float2(x00 * invT, y00 * invT);
    Pg[(pb + 1) * NCHN + pc] = make_float2(x10 * invT, y10 * invT);
  }
}

// ---------------- LU solve with partial pivoting (complex128) ----------------
__global__ void solve_kernel(const float2* __restrict__ R, const float2* __restrict__ P,
                             float* __restrict__ gout, float2* __restrict__ gct) {
  __shared__ double2 A[TAPS][TAPS];
  __shared__ double2 Bm[TAPS][NCHN];
  __shared__ int piv;
  int g = blockIdx.x;
  int tid = threadIdx.x;
  int s = g & 1;
  int bf = g >> 1;
  int f = bf % NFREQ;
  int b = bf / NFREQ;
  int bs = b * NSPK + s;

  for (int i = tid; i < TAPS * TAPS; i += 64) {
    float2 r = R[(size_t)g * TAPS * TAPS + i];
    A[i / TAPS][i % TAPS] = make_double2((double)r.x, (double)r.y);
  }
  for (int i = tid; i < TAPS * NCHN; i += 64) {
    float2 p = P[(size_t)g * TAPS * NCHN + i];
    Bm[i / NCHN][i % NCHN] = make_double2((double)p.x, (double)p.y);
  }
  __syncthreads();
  if (tid < TAPS) A[tid][tid].x += LAMBDA_REG;
  __syncthreads();

  for (int k = 0; k < TAPS; ++k) {
    if (tid == 0) {
      int r = k;
      double best = fabs(A[k][k].x) + fabs(A[k][k].y);
      for (int i = k + 1; i < TAPS; ++i) {
        double v = fabs(A[i][k].x) + fabs(A[i][k].y);
        if (v > best) { best = v; r = i; }
      }
      piv = r;
    }
    __syncthreads();
    int r = piv;
    if (r != k) {
      if (tid < TAPS) {
        double2 tmp = A[k][tid]; A[k][tid] = A[r][tid]; A[r][tid] = tmp;
      } else if (tid < TAPS + NCHN) {
        int c = tid - TAPS;
        double2 tmp = Bm[k][c]; Bm[k][c] = Bm[r][c]; Bm[r][c] = tmp;
      }
    }
    __syncthreads();
    double2 akk = A[k][k];
    double den = akk.x * akk.x + akk.y * akk.y;
    if (tid > k && tid < TAPS) {
      double2 a = A[tid][k];
      A[tid][k] = make_double2((a.x * akk.x + a.y * akk.y) / den,
                               (a.y * akk.x - a.x * akk.y) / den);
    }
    __syncthreads();
    int nr = TAPS - 1 - k;
    int nc = nr + NCHN;
    for (int idx = tid; idx < nr * nc; idx += 64) {
      int i = k + 1 + idx / nc;
      int jj = idx % nc;
      double2 mlt = A[i][k];
      if (jj < nr) {
        int j = k + 1 + jj;
        double2 u = A[k][j];
        A[i][j].x -= mlt.x * u.x - mlt.y * u.y;
        A[i][j].y -= mlt.x * u.y + mlt.y * u.x;
      } else {
        int c = jj - nr;
        double2 u = Bm[k][c];
        Bm[i][c].x -= mlt.x * u.x - mlt.y * u.y;
        Bm[i][c].y -= mlt.x * u.y + mlt.y * u.x;
      }
    }
    __syncthreads();
  }

  if (tid < NCHN) {
    int c = tid;
    for (int k = TAPS - 1; k >= 0; --k) {
      double sx = Bm[k][c].x, sy = Bm[k][c].y;
      for (int j = k + 1; j < TAPS; ++j) {
        double2 u = A[k][j], xv = Bm[j][c];
        sx -= u.x * xv.x - u.y * xv.y;
        sy -= u.x * xv.y + u.y * xv.x;
      }
      double2 akk = A[k][k];
      double den = akk.x * akk.x + akk.y * akk.y;
      Bm[k][c] = make_double2((sx * akk.x + sy * akk.y) / den,
                              (sy * akk.x - sx * akk.y) / den);
    }
  }
  __syncthreads();

  for (int i = tid; i < TAPS * NCHN; i += 64) {
    int p = i / NCHN, c = i - p * NCHN;
    double2 gv = Bm[p][c];
    float gx = (float)gv.x, gy = (float)(-gv.y);  // conj(G)
    gout[(size_t)g * TAPS * NCHN + i] = gx;       // float32, real part only
    gct[(((size_t)bs * TAPS + p) * NCHN + c) * NFREQ + f] = make_float2(gx, gy);
  }
}

// ---------------- ret + inverse FFT (dual-frame, XCD-swizzled) ----------------
__global__ void ret_ifft_kernel(const float2* __restrict__ spht, const float2* __restrict__ gct,
                                float* __restrict__ frames) {
  __shared__ float2 buf[2 * NFFT];
  constexpr int NBLK = NSIG * NCH2;
  int bid = blockIdx.x;
  int blk = (bid & 7) * (NBLK / 8) + (bid >> 3);  // XCD-aware swizzle
  int ch = blk % NCH2;
  int sc = blk / NCH2;
  int t0 = ch * 2;
  bool dual = (t0 + 1 < NT);
  int c = sc % NCHN;
  int bs = sc / NCHN;
  int tid = threadIdx.x;

  const float2* gbase = gct + ((size_t)bs * TAPS * NCHN + c) * NFREQ;
  const float2* ysig = spht + (size_t)bs * NT * NFREQ;
  for (int f = tid; f < NFREQ; f += 256) {
    float sx0 = 0.0f, sy0 = 0.0f, sx1 = 0.0f, sy1 = 0.0f;
    float2 gprev = make_float2(0.0f, 0.0f);
#pragma unroll
    for (int k = 0; k <= TAPS; ++k) {  // k = p(frame0); p(frame1) = k-1
      int u = t0 - (TAPS - 1) + k;
      float2 y = (u >= 0 && u < NT) ? ysig[(size_t)u * NFREQ + f] : make_float2(0.0f, 0.0f);
      float2 gc = (k < TAPS) ? gbase[(size_t)k * NCHN * NFREQ + f] : make_float2(0.0f, 0.0f);
      if (k < TAPS) {
        sx0 += y.x * gc.x - y.y * gc.y;
        sy0 += y.x * gc.y + y.y * gc.x;
      }
      if (k >= 1) {
        sx1 += y.x * gprev.x - y.y * gprev.y;
        sy1 += y.x * gprev.y + y.y * gprev.x;
      }
      gprev = gc;
    }
    int r = rev9(f);
    buf[r] = make_float2(sx0, sy0);
    buf[NFFT + r] = make_float2(sx1, sy1);
    if (f > 0 && f < NFFT / 2) {
      int r2 = rev9(NFFT - f);
      buf[r2] = make_float2(sx0, -sy0);
      buf[NFFT + r2] = make_float2(sx1, -sy1);
    }
  }
  __syncthreads();
  fft512_dual(buf, tid, +1.0f);

  float* frow = frames + ((size_t)sc * NT + t0) * NFFT;
  for (int n = tid; n < NFFT; n += 256) {
    float w = __sinf(PI_F * (float)n / (float)NFFT);
    frow[n] = buf[n].x * (1.0f / (float)NFFT) * w;
    if (dual) frow[NFFT + n] = buf[NFFT + n].x * (1.0f / (float)NFFT) * w;
  }
}

// ---------------- overlap-add + env normalize + crop (float32 out) ----------------
__global__ void ola_kernel(const float* __restrict__ frames, float* __restrict__ out) {
  int i = blockIdx.x * 256 + threadIdx.x;
  if (i >= NSIG * LSIG) return;
  int sig = i / LSIG;
  int l = i - sig * LSIG;
  int lp = l + NFFT / 2;
  int j0 = max(0, (lp - (NFFT - HOPSZ)) / HOPSZ);
  int j1 = min(NT - 1, lp / HOPSZ);
  float acc = 0.0f;
  for (int j = j0; j <= j1; ++j) {
    int n = lp - j * HOPSZ;
    acc += frames[((size_t)sig * NT + j) * NFFT + n];
  }
  float env;
  if (j1 - j0 == 3) {
    env = 2.0f;  // sum sin^2(theta + k*pi/4), k=0..3 == 2 exactly
  } else {
    env = 0.0f;
    for (int j = j0; j <= j1; ++j) {
      int n = lp - j * HOPSZ;
      float w = __sinf(PI_F * (float)n / (float)NFFT);
      env += w * w;
    }
    if (env <= 1e-11f) env = 1.0f;
  }
  out[(size_t)G_ELEMS + i] = acc / env;
}

}  // namespace

extern "C" void kernel_launch(void* const* d_in, const int* in_sizes, int n_in,
                              void* d_out, int out_size, void* d_ws, size_t ws_size,
                              hipStream_t stream) {
  const float* ref = (const float*)d_in[0];
  const float* mix = (const float*)d_in[1];
  if (n_in >= 2 && in_sizes[0] > in_sizes[1]) {
    const float* tmp = ref; ref = mix; mix = tmp;
  }
  char* ws = (char*)d_ws;

  float2*  sph   = (float2*)(ws + SPH_B);
  float2*  spht  = (float2*)(ws + SPHT_B);
  float2*  mxs   = (float2*)(ws + MXS_B);
  float*   power = (float*)(ws + POW_B);
  float*   mx    = (float*)(ws + MX_B);
  float2*  R     = (float2*)(ws + R_B);
  float2*  P     = (float2*)(ws + P_B);
  float2*  gct   = (float2*)(ws + GCT_B);
  float*   frames= (float*)(ws + FRM_B);
  float*   out   = (float*)d_out;

  stft_kernel<<<dim3((NB * NSPK + NB * NCHN) * NCH2), dim3(256), 0, stream>>>(ref, mix, sph, spht, mxs);
  power_kernel<<<dim3((NB * NFREQ * NT + 255) / 256), dim3(256), 0, stream>>>(mxs, power);
  max_kernel<<<dim3(NB), dim3(256), 0, stream>>>(power, mx);
  rp_kernel<<<dim3(NG), dim3(512), 0, stream>>>(sph, mxs, power, mx, R, P);
  solve_kernel<<<dim3(NG), dim3(64), 0, stream>>>(R, P, out, gct);
  ret_ifft_kernel<<<dim3(NSIG * NCH2), dim3(256), 0, stream>>>(spht, gct, frames);
  ola_kernel<<<dim3((NSIG * LSIG + 255) / 256), dim3(256), 0, stream>>>(frames, out);
}

// Round 15
// 368.277 us; speedup vs baseline: 1.5306x; 1.0319x over previous
//
#include <hip/hip_runtime.h>
#include <math.h>

namespace {

constexpr int NB = 4, NSPK = 2, NCHN = 6;
constexpr int LSIG = 64000;
constexpr int NFFT = 512, HOPSZ = 128, NFREQ = 257;
constexpr int NT = 505;               // frames
constexpr int TAPS = 20;
constexpr int NG = NB * NFREQ * NSPK; // 2056 systems
constexpr int NSIG = NB * NSPK * NCHN; // 48 istft signals
constexpr float PI_F = 3.14159265358979323846f;
constexpr double LAMBDA_REG = 2e-4;
constexpr float FCP_EPS_F = 1e-3f;
constexpr int G_ELEMS = NG * TAPS * NCHN; // 246720 floats (real part only)
constexpr int NCH4 = (NT + 3) / 4;    // 127 four-frame chunks (last has 1)
constexpr int YPAD_N = TAPS + 2 + NT; // 527: [0..18]=0, [19+u]=Y[u], tail zeros
constexpr int NR_TILES = 55;          // 2x2 tiles of lower triangle (10x10 tile grid)
constexpr int NP_THREADS = 60;        // 10 p-pairs x 6 channels

constexpr size_t WS_ALIGN = 256;
constexpr size_t align_up(size_t x) { return (x + WS_ALIGN - 1) & ~(WS_ALIGN - 1); }

// ws byte offsets
constexpr size_t SPH_B  = 0;                                        // [8][257][505] float2
constexpr size_t SPH_SZ = (size_t)NB * NSPK * NFREQ * NT * 8;
constexpr size_t SPHT_B = align_up(SPH_B + SPH_SZ);                 // [8][505][257] float2
constexpr size_t MXS_B  = align_up(SPHT_B + SPH_SZ);                // [24][257][505] float2
constexpr size_t MXS_SZ = (size_t)NB * NCHN * NFREQ * NT * 8;
constexpr size_t POW_B  = align_up(MXS_B + MXS_SZ);                 // [4][257][505] float
constexpr size_t POW_SZ = (size_t)NB * NFREQ * NT * 4;
constexpr size_t MX_B   = align_up(POW_B + POW_SZ);                 // [4] float
constexpr size_t R_B    = align_up(MX_B + (size_t)NB * 4);          // [2056][400] float2
constexpr size_t R_SZ   = (size_t)NG * TAPS * TAPS * 8;
constexpr size_t P_B    = align_up(R_B + R_SZ);                     // [2056][120] float2
constexpr size_t P_SZ   = (size_t)NG * TAPS * NCHN * 8;
constexpr size_t GCT_B  = align_up(P_B + P_SZ);                     // [8][20][6][257] float2
constexpr size_t GCT_SZ = (size_t)NB * NSPK * TAPS * NCHN * NFREQ * 8;
constexpr size_t FRM_B  = align_up(GCT_B + GCT_SZ);                 // [48][505][512] float

__device__ __forceinline__ int rev9(int n) { return (int)(__brev((unsigned)n) >> 23); }

// Quad in-LDS radix-2 DIT FFT: FOUR independent 512-pt transforms.
// Twiddle computed once/stage; 4 butterflies/thread/stage; barriers amortized 4x.
__device__ __forceinline__ void fft512_quad(float2* buf, int tid, float sign) {
#pragma unroll
  for (int s = 1; s <= 9; ++s) {
    int half = 1 << (s - 1);
    int blk = tid >> (s - 1);
    int pos = tid & (half - 1);
    int i0 = (blk << s) + pos;
    int i1 = i0 + half;
    float ang = sign * 2.0f * PI_F * (float)pos / (float)(half << 1);
    float sn, cs;
    __sincosf(ang, &sn, &cs);
#pragma unroll
    for (int j = 0; j < 4; ++j) {
      float2 u = buf[j * NFFT + i0], v = buf[j * NFFT + i1];
      float2 vw = make_float2(v.x * cs - v.y * sn, v.x * sn + v.y * cs);
      buf[j * NFFT + i0] = make_float2(u.x + vw.x, u.y + vw.y);
      buf[j * NFFT + i1] = make_float2(u.x - vw.x, u.y - vw.y);
    }
    __syncthreads();
  }
}

// ---------------- STFT (quad-frame radix-2 FFT) ----------------
// grid: 32 * NCH4 blocks, 256 threads. Frames t0..t0+3 per block (masked tail).
__global__ void stft_kernel(const float* __restrict__ ref, const float* __restrict__ mix,
                            float2* __restrict__ sph, float2* __restrict__ spht,
                            float2* __restrict__ mxs) {
  __shared__ float2 buf[4 * NFFT];
  int blk = blockIdx.x;
  int sig = blk / NCH4;
  int ch = blk - sig * NCH4;
  int t0 = ch * 4;
  int nv = min(4, NT - t0);
  int tid = threadIdx.x;
  bool is_ref = sig < NB * NSPK;
  int m = is_ref ? sig : (sig - NB * NSPK);
  const float* src = is_ref ? (ref + (size_t)m * LSIG) : (mix + (size_t)m * LSIG);

  for (int n = tid; n < NFFT; n += 256) {
    float w = __sinf(PI_F * (float)n / (float)NFFT);  // sqrt-hann
    int r = rev9(n);
    int g0 = t0 * HOPSZ + n - NFFT / 2;
#pragma unroll
    for (int j = 0; j < 4; ++j) {
      int gg = g0 + j * HOPSZ;
      float v = (j < nv && gg >= 0 && gg < LSIG) ? src[gg] : 0.0f;
      buf[j * NFFT + r] = make_float2(v * w, 0.0f);
    }
  }
  __syncthreads();
  fft512_quad(buf, tid, -1.0f);

  if (is_ref) {
    float2* d1 = sph + (size_t)m * NFREQ * NT;
    float2* d2 = spht + ((size_t)m * NT + t0) * NFREQ;
    for (int f = tid; f < NFREQ; f += 256) {
#pragma unroll
      for (int j = 0; j < 4; ++j) {
        if (j < nv) {
          float2 v = buf[j * NFFT + f];
          d1[(size_t)f * NT + t0 + j] = v;
          d2[(size_t)j * NFREQ + f] = v;
        }
      }
    }
  } else {
    float2* d1 = mxs + (size_t)m * NFREQ * NT;
    for (int f = tid; f < NFREQ; f += 256) {
#pragma unroll
      for (int j = 0; j < 4; ++j)
        if (j < nv) d1[(size_t)f * NT + t0 + j] = buf[j * NFFT + f];
    }
  }
}

// ---------------- power ----------------
__global__ void power_kernel(const float2* __restrict__ mxs, float* __restrict__ power) {
  int i = blockIdx.x * 256 + threadIdx.x;
  if (i >= NB * NFREQ * NT) return;
  int b = i / (NFREQ * NT);
  int r = i - b * (NFREQ * NT);
  float acc = 0.0f;
#pragma unroll
  for (int c = 0; c < NCHN; ++c) {
    float2 v = mxs[(size_t)(b * NCHN + c) * NFREQ * NT + r];
    acc += v.x * v.x + v.y * v.y;
  }
  power[i] = acc * (1.0f / (float)NCHN);
}

// ---------------- per-batch max ----------------
__global__ void max_kernel(const float* __restrict__ power, float* __restrict__ mx) {
  int b = blockIdx.x;
  const float* p = power + (size_t)b * NFREQ * NT;
  float m = 0.0f;
  for (int i = threadIdx.x; i < NFREQ * NT; i += 256) m = fmaxf(m, p[i]);
#pragma unroll
  for (int off = 32; off > 0; off >>= 1) m = fmaxf(m, __shfl_down(m, off, 64));
  __shared__ float sm[4];
  int wave = threadIdx.x >> 6, lane = threadIdx.x & 63;
  if (lane == 0) sm[wave] = m;
  __syncthreads();
  if (threadIdx.x == 0) mx[b] = fmaxf(fmaxf(sm[0], sm[1]), fmaxf(sm[2], sm[3]));
}

// ---------------- R / P accumulation (register-tiled, 4-way t-split, 512 thr) ----------------
// 8 waves: waves 0-3 = R 2x2 tiles over t-quarters; waves 4-7 = P 2x1 tiles.
// R inner loop folds w into the a-side per t (4 mul + 16 fma for 4 pairs).
__global__ void rp_kernel(const float2* __restrict__ sph, const float2* __restrict__ mxs,
                          const float* __restrict__ power, const float* __restrict__ mx,
                          float2* __restrict__ R, float2* __restrict__ P) {
  __shared__ float2 Ypad[YPAD_N];      // [0..18]=0, [19+u]=Y[u], tail zeros
  __shared__ float2 MWsh[NCHN][NT];    // w[t] * conj(M[c][t]); scratch after loops
  __shared__ float Wsh[NT];
  int g = blockIdx.x;
  int s = g & 1;
  int bf = g >> 1;
  int f = bf % NFREQ;
  int b = bf / NFREQ;
  int tid = threadIdx.x;

  const float2* yrow = sph + ((size_t)(b * NSPK + s) * NFREQ + f) * NT;
  const float* prow = power + ((size_t)b * NFREQ + f) * NT;
  float add = mx[b] * FCP_EPS_F + 1e-6f;
  for (int t = tid; t < NT; t += 512) Wsh[t] = 1.0f / (prow[t] + add);
  for (int i = tid; i < YPAD_N; i += 512) {
    bool in = (i >= TAPS - 1) && (i < TAPS - 1 + NT);
    Ypad[i] = in ? yrow[i - (TAPS - 1)] : make_float2(0.0f, 0.0f);
  }
  __syncthreads();
  for (int i = tid; i < NCHN * NT; i += 512) {
    int c = i / NT, t = i - c * NT;
    float2 m = mxs[((size_t)(b * NCHN + c) * NFREQ + f) * NT + t];
    float w = Wsh[t];
    MWsh[c][t] = make_float2(w * m.x, -w * m.y);
  }
  __syncthreads();

  const float invT = 1.0f / (float)NT;
  const int TQ[5] = {0, 126, 252, 378, NT};
  int wave = tid >> 6;
  int lane = tid & 63;
  bool isR = (wave < 4) && (lane < NR_TILES);
  bool isP = (wave >= 4) && (lane < NP_THREADS);

  float x00 = 0.f, y00 = 0.f, x01 = 0.f, y01 = 0.f;
  float x10 = 0.f, y10 = 0.f, x11 = 0.f, y11 = 0.f;
  int pb = 0, qb = 0, pc = 0;

  if (isR) {
    int seg = wave;
    int tlo = TQ[seg], thi = TQ[seg + 1];
    int I = (int)((sqrtf(8.0f * (float)lane + 1.0f) - 1.0f) * 0.5f);
    while ((I + 1) * (I + 2) / 2 <= lane) ++I;
    while (I * (I + 1) / 2 > lane) --I;
    int J = lane - I * (I + 1) / 2;
    pb = 2 * I; qb = 2 * J;
    float2 a0 = Ypad[pb + tlo], a1 = Ypad[pb + tlo + 1];
    float2 b0 = Ypad[qb + tlo], b1 = Ypad[qb + tlo + 1];
    for (int t = tlo; t < thi; ++t) {
      float w = Wsh[t];
      float wax0 = w * a0.x, way0 = w * a0.y;
      float wax1 = w * a1.x, way1 = w * a1.y;
      x00 = fmaf(wax0, b0.x, fmaf(way0, b0.y, x00));
      y00 = fmaf(way0, b0.x, fmaf(-wax0, b0.y, y00));
      x01 = fmaf(wax0, b1.x, fmaf(way0, b1.y, x01));
      y01 = fmaf(way0, b1.x, fmaf(-wax0, b1.y, y01));
      x10 = fmaf(wax1, b0.x, fmaf(way1, b0.y, x10));
      y10 = fmaf(way1, b0.x, fmaf(-wax1, b0.y, y10));
      x11 = fmaf(wax1, b1.x, fmaf(way1, b1.y, x11));
      y11 = fmaf(way1, b1.x, fmaf(-wax1, b1.y, y11));
      a0 = a1; a1 = Ypad[pb + 2 + t];   // slide window
      b0 = b1; b1 = Ypad[qb + 2 + t];
    }
  } else if (isP) {
    int seg = wave - 4;
    int tlo = TQ[seg], thi = TQ[seg + 1];
    int ih = lane / NCHN;
    pc = lane - ih * NCHN;
    pb = 2 * ih;
    float2 a0 = Ypad[pb + tlo], a1 = Ypad[pb + tlo + 1];
    const float2* MW = &MWsh[pc][0];
    for (int t = tlo; t < thi; ++t) {
      float2 mw = MW[t];
      x00 += a0.x * mw.x - a0.y * mw.y;
      y00 += a0.x * mw.y + a0.y * mw.x;
      x10 += a1.x * mw.x - a1.y * mw.y;
      y10 += a1.x * mw.y + a1.y * mw.x;
      a0 = a1; a1 = Ypad[pb + 2 + t];
    }
  }
  __syncthreads();    // all loop reads (Ypad, MWsh, Wsh) complete

  float* scratch = (float*)MWsh;  // dead now; need 2040 floats of 24240
  if (isR && wave >= 1) {
    float* d = scratch + ((wave - 1) * NR_TILES + lane) * 8;
    d[0] = x00; d[1] = y00; d[2] = x01; d[3] = y01;
    d[4] = x10; d[5] = y10; d[6] = x11; d[7] = y11;
  }
  if (isP && wave >= 5) {
    float* d = scratch + 3 * NR_TILES * 8 + ((wave - 5) * NP_THREADS + lane) * 4;
    d[0] = x00; d[1] = y00; d[2] = x10; d[3] = y10;
  }
  __syncthreads();

  if (isR && wave == 0) {
#pragma unroll
    for (int sgi = 0; sgi < 3; ++sgi) {
      const float* d = scratch + (sgi * NR_TILES + lane) * 8;
      x00 += d[0]; y00 += d[1]; x01 += d[2]; y01 += d[3];
      x10 += d[4]; y10 += d[5]; x11 += d[6]; y11 += d[7];
    }
    float2* Rg = R + (size_t)g * TAPS * TAPS;
#define STORE_R(p_, q_, xx, yy)                                       \
    if ((p_) >= (q_)) {                                                \
      float rx = (xx) * invT, ry = (yy) * invT;                        \
      Rg[(p_) * TAPS + (q_)] = make_float2(rx, ry);                    \
      if ((p_) != (q_)) Rg[(q_) * TAPS + (p_)] = make_float2(rx, -ry); \
    }
    STORE_R(pb, qb, x00, y00)
    STORE_R(pb, qb + 1, x01, y01)
    STORE_R(pb + 1, qb, x10, y10)
    STORE_R(pb + 1, qb + 1, x11, y11)
#undef STORE_R
  }
  if (isP && wave == 4) {
#pragma unroll
    for (int sgi = 0; sgi < 3; ++sgi) {
      const float* d = scratch + 3 * NR_TILES * 8 + (sgi * NP_THREADS + lane) * 4;
      x00 += d[0]; y00 += d[1]; x10 += d[2]; y10 += d[3];
    }
    float2* Pg = P + (size_t)g * TAPS * NCHN;
    Pg[pb * NCHN + pc] = make_float2(x00 * invT, y00 * invT);
    Pg[(pb + 1) * NCHN + pc] = make_float2(x10 * invT, y10 * invT);
  }
}

// ---------------- LU solve with partial pivoting (complex128) ----------------
__global__ void solve_kernel(const float2* __restrict__ R, const float2* __restrict__ P,
                             float* __restrict__ gout, float2* __restrict__ gct) {
  __shared__ double2 A[TAPS][TAPS];
  __shared__ double2 Bm[TAPS][NCHN];
  __shared__ int piv;
  int g = blockIdx.x;
  int tid = threadIdx.x;
  int s = g & 1;
  int bf = g >> 1;
  int f = bf % NFREQ;
  int b = bf / NFREQ;
  int bs = b * NSPK + s;

  for (int i = tid; i < TAPS * TAPS; i += 64) {
    float2 r = R[(size_t)g * TAPS * TAPS + i];
    A[i / TAPS][i % TAPS] = make_double2((double)r.x, (double)r.y);
  }
  for (int i = tid; i < TAPS * NCHN; i += 64) {
    float2 p = P[(size_t)g * TAPS * NCHN + i];
    Bm[i / NCHN][i % NCHN] = make_double2((double)p.x, (double)p.y);
  }
  __syncthreads();
  if (tid < TAPS) A[tid][tid].x += LAMBDA_REG;
  __syncthreads();

  for (int k = 0; k < TAPS; ++k) {
    if (tid == 0) {
      int r = k;
      double best = fabs(A[k][k].x) + fabs(A[k][k].y);
      for (int i = k + 1; i < TAPS; ++i) {
        double v = fabs(A[i][k].x) + fabs(A[i][k].y);
        if (v > best) { best = v; r = i; }
      }
      piv = r;
    }
    __syncthreads();
    int r = piv;
    if (r != k) {
      if (tid < TAPS) {
        double2 tmp = A[k][tid]; A[k][tid] = A[r][tid]; A[r][tid] = tmp;
      } else if (tid < TAPS + NCHN) {
        int c = tid - TAPS;
        double2 tmp = Bm[k][c]; Bm[k][c] = Bm[r][c]; Bm[r][c] = tmp;
      }
    }
    __syncthreads();
    double2 akk = A[k][k];
    double den = akk.x * akk.x + akk.y * akk.y;
    if (tid > k && tid < TAPS) {
      double2 a = A[tid][k];
      A[tid][k] = make_double2((a.x * akk.x + a.y * akk.y) / den,
                               (a.y * akk.x - a.x * akk.y) / den);
    }
    __syncthreads();
    int nr = TAPS - 1 - k;
    int nc = nr + NCHN;
    for (int idx = tid; idx < nr * nc; idx += 64) {
      int i = k + 1 + idx / nc;
      int jj = idx % nc;
      double2 mlt = A[i][k];
      if (jj < nr) {
        int j = k + 1 + jj;
        double2 u = A[k][j];
        A[i][j].x -= mlt.x * u.x - mlt.y * u.y;
        A[i][j].y -= mlt.x * u.y + mlt.y * u.x;
      } else {
        int c = jj - nr;
        double2 u = Bm[k][c];
        Bm[i][c].x -= mlt.x * u.x - mlt.y * u.y;
        Bm[i][c].y -= mlt.x * u.y + mlt.y * u.x;
      }
    }
    __syncthreads();
  }

  if (tid < NCHN) {
    int c = tid;
    for (int k = TAPS - 1; k >= 0; --k) {
      double sx = Bm[k][c].x, sy = Bm[k][c].y;
      for (int j = k + 1; j < TAPS; ++j) {
        double2 u = A[k][j], xv = Bm[j][c];
        sx -= u.x * xv.x - u.y * xv.y;
        sy -= u.x * xv.y + u.y * xv.x;
      }
      double2 akk = A[k][k];
      double den = akk.x * akk.x + akk.y * akk.y;
      Bm[k][c] = make_double2((sx * akk.x + sy * akk.y) / den,
                              (sy * akk.x - sx * akk.y) / den);
    }
  }
  __syncthreads();

  for (int i = tid; i < TAPS * NCHN; i += 64) {
    int p = i / NCHN, c = i - p * NCHN;
    double2 gv = Bm[p][c];
    float gx = (float)gv.x, gy = (float)(-gv.y);  // conj(G)
    gout[(size_t)g * TAPS * NCHN + i] = gx;       // float32, real part only
    gct[(((size_t)bs * TAPS + p) * NCHN + c) * NFREQ + f] = make_float2(gx, gy);
  }
}

// ---------------- ret + inverse FFT (quad-frame, XCD-swizzled) ----------------
// grid: NSIG*NCH4 = 6096 blocks (%8==0). Frames t0..t0+3 share y stream and a
// 3-deep G ring: 43 loads for 4 spectra. Invalid tail frames computed, not stored.
__global__ void ret_ifft_kernel(const float2* __restrict__ spht, const float2* __restrict__ gct,
                                float* __restrict__ frames) {
  __shared__ float2 buf[4 * NFFT];
  constexpr int NBLK = NSIG * NCH4;
  int bid = blockIdx.x;
  int blk = (bid & 7) * (NBLK / 8) + (bid >> 3);  // XCD-aware swizzle
  int ch = blk % NCH4;
  int sc = blk / NCH4;
  int t0 = ch * 4;
  int nv = min(4, NT - t0);
  int c = sc % NCHN;
  int bs = sc / NCHN;
  int tid = threadIdx.x;

  const float2* gbase = gct + ((size_t)bs * TAPS * NCHN + c) * NFREQ;
  const float2* ysig = spht + (size_t)bs * NT * NFREQ;
  for (int f = tid; f < NFREQ; f += 256) {
    float sx0 = 0.f, sy0 = 0.f, sx1 = 0.f, sy1 = 0.f;
    float sx2 = 0.f, sy2 = 0.f, sx3 = 0.f, sy3 = 0.f;
    float2 g1p = make_float2(0.f, 0.f), g2p = make_float2(0.f, 0.f),
           g3p = make_float2(0.f, 0.f);
#pragma unroll
    for (int k = 0; k <= TAPS + 2; ++k) {  // frame j uses G[k-j]; ring holds zeros OOB
      int u = t0 - (TAPS - 1) + k;
      float2 y = (u >= 0 && u < NT) ? ysig[(size_t)u * NFREQ + f] : make_float2(0.f, 0.f);
      float2 gc = (k < TAPS) ? gbase[(size_t)k * NCHN * NFREQ + f] : make_float2(0.f, 0.f);
      sx0 += y.x * gc.x - y.y * gc.y;   sy0 += y.x * gc.y + y.y * gc.x;
      sx1 += y.x * g1p.x - y.y * g1p.y; sy1 += y.x * g1p.y + y.y * g1p.x;
      sx2 += y.x * g2p.x - y.y * g2p.y; sy2 += y.x * g2p.y + y.y * g2p.x;
      sx3 += y.x * g3p.x - y.y * g3p.y; sy3 += y.x * g3p.y + y.y * g3p.x;
      g3p = g2p; g2p = g1p; g1p = gc;
    }
    int r = rev9(f);
    buf[r] = make_float2(sx0, sy0);
    buf[NFFT + r] = make_float2(sx1, sy1);
    buf[2 * NFFT + r] = make_float2(sx2, sy2);
    buf[3 * NFFT + r] = make_float2(sx3, sy3);
    if (f > 0 && f < NFFT / 2) {
      int r2 = rev9(NFFT - f);
      buf[r2] = make_float2(sx0, -sy0);
      buf[NFFT + r2] = make_float2(sx1, -sy1);
      buf[2 * NFFT + r2] = make_float2(sx2, -sy2);
      buf[3 * NFFT + r2] = make_float2(sx3, -sy3);
    }
  }
  __syncthreads();
  fft512_quad(buf, tid, +1.0f);

  float* frow = frames + ((size_t)sc * NT + t0) * NFFT;
  for (int n = tid; n < NFFT; n += 256) {
    float w = __sinf(PI_F * (float)n / (float)NFFT);
#pragma unroll
    for (int j = 0; j < 4; ++j)
      if (j < nv) frow[(size_t)j * NFFT + n] = buf[j * NFFT + n].x * (1.0f / (float)NFFT) * w;
  }
}

// ---------------- overlap-add + env normalize + crop (float32 out) ----------------
__global__ void ola_kernel(const float* __restrict__ frames, float* __restrict__ out) {
  int i = blockIdx.x * 256 + threadIdx.x;
  if (i >= NSIG * LSIG) return;
  int sig = i / LSIG;
  int l = i - sig * LSIG;
  int lp = l + NFFT / 2;
  int j0 = max(0, (lp - (NFFT - HOPSZ)) / HOPSZ);
  int j1 = min(NT - 1, lp / HOPSZ);
  float acc = 0.0f;
  for (int j = j0; j <= j1; ++j) {
    int n = lp - j * HOPSZ;
    acc += frames[((size_t)sig * NT + j) * NFFT + n];
  }
  float env;
  if (j1 - j0 == 3) {
    env = 2.0f;  // sum sin^2(theta + k*pi/4), k=0..3 == 2 exactly
  } else {
    env = 0.0f;
    for (int j = j0; j <= j1; ++j) {
      int n = lp - j * HOPSZ;
      float w = __sinf(PI_F * (float)n / (float)NFFT);
      env += w * w;
    }
    if (env <= 1e-11f) env = 1.0f;
  }
  out[(size_t)G_ELEMS + i] = acc / env;
}

}  // namespace

extern "C" void kernel_launch(void* const* d_in, const int* in_sizes, int n_in,
                              void* d_out, int out_size, void* d_ws, size_t ws_size,
                              hipStream_t stream) {
  const float* ref = (const float*)d_in[0];
  const float* mix = (const float*)d_in[1];
  if (n_in >= 2 && in_sizes[0] > in_sizes[1]) {
    const float* tmp = ref; ref = mix; mix = tmp;
  }
  char* ws = (char*)d_ws;

  float2*  sph   = (float2*)(ws + SPH_B);
  float2*  spht  = (float2*)(ws + SPHT_B);
  float2*  mxs   = (float2*)(ws + MXS_B);
  float*   power = (float*)(ws + POW_B);
  float*   mx    = (float*)(ws + MX_B);
  float2*  R     = (float2*)(ws + R_B);
  float2*  P     = (float2*)(ws + P_B);
  float2*  gct   = (float2*)(ws + GCT_B);
  float*   frames= (float*)(ws + FRM_B);
  float*   out   = (float*)d_out;

  stft_kernel<<<dim3((NB * NSPK + NB * NCHN) * NCH4), dim3(256), 0, stream>>>(ref, mix, sph, spht, mxs);
  power_kernel<<<dim3((NB * NFREQ * NT + 255) / 256), dim3(256), 0, stream>>>(mxs, power);
  max_kernel<<<dim3(NB), dim3(256), 0, stream>>>(power, mx);
  rp_kernel<<<dim3(NG), dim3(512), 0, stream>>>(sph, mxs, power, mx, R, P);
  solve_kernel<<<dim3(NG), dim3(64), 0, stream>>>(R, P, out, gct);
  ret_ifft_kernel<<<dim3(NSIG * NCH4), dim3(256), 0, stream>>>(spht, gct, frames);
  ola_kernel<<<dim3((NSIG * LSIG + 255) / 256), dim3(256), 0, stream>>>(frames, out);
}

// Round 16
// 367.585 us; speedup vs baseline: 1.5335x; 1.0019x over previous
//
#include <hip/hip_runtime.h>
#include <math.h>

namespace {

constexpr int NB = 4, NSPK = 2, NCHN = 6;
constexpr int LSIG = 64000;
constexpr int NFFT = 512, HOPSZ = 128, NFREQ = 257;
constexpr int NT = 505;               // frames
constexpr int TAPS = 20;
constexpr int NG = NB * NFREQ * NSPK; // 2056 systems
constexpr int NSIG = NB * NSPK * NCHN; // 48 istft signals
constexpr float PI_F = 3.14159265358979323846f;
constexpr double LAMBDA_REG = 2e-4;
constexpr float FCP_EPS_F = 1e-3f;
constexpr int G_ELEMS = NG * TAPS * NCHN; // 246720 floats (real part only)
constexpr int NCH4 = (NT + 3) / 4;    // 127 four-frame chunks (last has 1)
constexpr int YPAD_N = TAPS + 2 + NT; // 527: [0..18]=0, [19+u]=Y[u], tail zeros
constexpr int NR_TILES = 55;          // 2x2 tiles of lower triangle (10x10 tile grid)
constexpr int NP_THREADS = 60;        // 10 p-pairs x 6 channels

constexpr size_t WS_ALIGN = 256;
constexpr size_t align_up(size_t x) { return (x + WS_ALIGN - 1) & ~(WS_ALIGN - 1); }

// ws byte offsets
constexpr size_t SPH_B  = 0;                                        // [8][257][505] float2
constexpr size_t SPH_SZ = (size_t)NB * NSPK * NFREQ * NT * 8;
constexpr size_t SPHT_B = align_up(SPH_B + SPH_SZ);                 // [8][505][257] float2
constexpr size_t MXS_B  = align_up(SPHT_B + SPH_SZ);                // [24][257][505] float2
constexpr size_t MXS_SZ = (size_t)NB * NCHN * NFREQ * NT * 8;
constexpr size_t POW_B  = align_up(MXS_B + MXS_SZ);                 // [4][257][505] float
constexpr size_t POW_SZ = (size_t)NB * NFREQ * NT * 4;
constexpr size_t MX_B   = align_up(POW_B + POW_SZ);                 // [4] float
constexpr size_t R_B    = align_up(MX_B + (size_t)NB * 4);          // [2056][400] float2
constexpr size_t R_SZ   = (size_t)NG * TAPS * TAPS * 8;
constexpr size_t P_B    = align_up(R_B + R_SZ);                     // [2056][120] float2
constexpr size_t P_SZ   = (size_t)NG * TAPS * NCHN * 8;
constexpr size_t GCT_B  = align_up(P_B + P_SZ);                     // [8][20][6][257] float2
constexpr size_t GCT_SZ = (size_t)NB * NSPK * TAPS * NCHN * NFREQ * 8;
constexpr size_t FRM_B  = align_up(GCT_B + GCT_SZ);                 // [48][505][512] float

__device__ __forceinline__ int rev9(int n) { return (int)(__brev((unsigned)n) >> 23); }

// Quad in-LDS radix-2 DIT FFT: FOUR independent 512-pt transforms.
__device__ __forceinline__ void fft512_quad(float2* buf, int tid, float sign) {
#pragma unroll
  for (int s = 1; s <= 9; ++s) {
    int half = 1 << (s - 1);
    int blk = tid >> (s - 1);
    int pos = tid & (half - 1);
    int i0 = (blk << s) + pos;
    int i1 = i0 + half;
    float ang = sign * 2.0f * PI_F * (float)pos / (float)(half << 1);
    float sn, cs;
    __sincosf(ang, &sn, &cs);
#pragma unroll
    for (int j = 0; j < 4; ++j) {
      float2 u = buf[j * NFFT + i0], v = buf[j * NFFT + i1];
      float2 vw = make_float2(v.x * cs - v.y * sn, v.x * sn + v.y * cs);
      buf[j * NFFT + i0] = make_float2(u.x + vw.x, u.y + vw.y);
      buf[j * NFFT + i1] = make_float2(u.x - vw.x, u.y - vw.y);
    }
    __syncthreads();
  }
}

// ---------------- STFT (quad-frame radix-2 FFT) ----------------
__global__ void stft_kernel(const float* __restrict__ ref, const float* __restrict__ mix,
                            float2* __restrict__ sph, float2* __restrict__ spht,
                            float2* __restrict__ mxs) {
  __shared__ float2 buf[4 * NFFT];
  int blk = blockIdx.x;
  int sig = blk / NCH4;
  int ch = blk - sig * NCH4;
  int t0 = ch * 4;
  int nv = min(4, NT - t0);
  int tid = threadIdx.x;
  bool is_ref = sig < NB * NSPK;
  int m = is_ref ? sig : (sig - NB * NSPK);
  const float* src = is_ref ? (ref + (size_t)m * LSIG) : (mix + (size_t)m * LSIG);

  for (int n = tid; n < NFFT; n += 256) {
    float w = __sinf(PI_F * (float)n / (float)NFFT);  // sqrt-hann
    int r = rev9(n);
    int g0 = t0 * HOPSZ + n - NFFT / 2;
#pragma unroll
    for (int j = 0; j < 4; ++j) {
      int gg = g0 + j * HOPSZ;
      float v = (j < nv && gg >= 0 && gg < LSIG) ? src[gg] : 0.0f;
      buf[j * NFFT + r] = make_float2(v * w, 0.0f);
    }
  }
  __syncthreads();
  fft512_quad(buf, tid, -1.0f);

  if (is_ref) {
    float2* d1 = sph + (size_t)m * NFREQ * NT;
    float2* d2 = spht + ((size_t)m * NT + t0) * NFREQ;
    for (int f = tid; f < NFREQ; f += 256) {
#pragma unroll
      for (int j = 0; j < 4; ++j) {
        if (j < nv) {
          float2 v = buf[j * NFFT + f];
          d1[(size_t)f * NT + t0 + j] = v;
          d2[(size_t)j * NFREQ + f] = v;
        }
      }
    }
  } else {
    float2* d1 = mxs + (size_t)m * NFREQ * NT;
    for (int f = tid; f < NFREQ; f += 256) {
#pragma unroll
      for (int j = 0; j < 4; ++j)
        if (j < nv) d1[(size_t)f * NT + t0 + j] = buf[j * NFFT + f];
    }
  }
}

// ---------------- power ----------------
__global__ void power_kernel(const float2* __restrict__ mxs, float* __restrict__ power) {
  int i = blockIdx.x * 256 + threadIdx.x;
  if (i >= NB * NFREQ * NT) return;
  int b = i / (NFREQ * NT);
  int r = i - b * (NFREQ * NT);
  float acc = 0.0f;
#pragma unroll
  for (int c = 0; c < NCHN; ++c) {
    float2 v = mxs[(size_t)(b * NCHN + c) * NFREQ * NT + r];
    acc += v.x * v.x + v.y * v.y;
  }
  power[i] = acc * (1.0f / (float)NCHN);
}

// ---------------- per-batch max ----------------
__global__ void max_kernel(const float* __restrict__ power, float* __restrict__ mx) {
  int b = blockIdx.x;
  const float* p = power + (size_t)b * NFREQ * NT;
  float m = 0.0f;
  for (int i = threadIdx.x; i < NFREQ * NT; i += 256) m = fmaxf(m, p[i]);
#pragma unroll
  for (int off = 32; off > 0; off >>= 1) m = fmaxf(m, __shfl_down(m, off, 64));
  __shared__ float sm[4];
  int wave = threadIdx.x >> 6, lane = threadIdx.x & 63;
  if (lane == 0) sm[wave] = m;
  __syncthreads();
  if (threadIdx.x == 0) mx[b] = fmaxf(fmaxf(sm[0], sm[1]), fmaxf(sm[2], sm[3]));
}

// ---------------- R / P accumulation (register-tiled, 4-way t-split, unroll-2) ----------------
// 8 waves: waves 0-3 = R 2x2 tiles over t-quarters; waves 4-7 = P 2x1 tiles.
// Unroll-2 with register rotation: two sliding loads merge into one aligned
// ds_read_b128 (t stays even: quarter starts 0/126/252/378) and movs rename away.
__global__ void rp_kernel(const float2* __restrict__ sph, const float2* __restrict__ mxs,
                          const float* __restrict__ power, const float* __restrict__ mx,
                          float2* __restrict__ R, float2* __restrict__ P) {
  __shared__ float2 Ypad[YPAD_N];      // [0..18]=0, [19+u]=Y[u], tail zeros
  __shared__ float2 MWsh[NCHN][NT];    // w[t] * conj(M[c][t]); scratch after loops
  __shared__ float Wsh[NT];
  int g = blockIdx.x;
  int s = g & 1;
  int bf = g >> 1;
  int f = bf % NFREQ;
  int b = bf / NFREQ;
  int tid = threadIdx.x;

  const float2* yrow = sph + ((size_t)(b * NSPK + s) * NFREQ + f) * NT;
  const float* prow = power + ((size_t)b * NFREQ + f) * NT;
  float add = mx[b] * FCP_EPS_F + 1e-6f;
  for (int t = tid; t < NT; t += 512) Wsh[t] = 1.0f / (prow[t] + add);
  for (int i = tid; i < YPAD_N; i += 512) {
    bool in = (i >= TAPS - 1) && (i < TAPS - 1 + NT);
    Ypad[i] = in ? yrow[i - (TAPS - 1)] : make_float2(0.0f, 0.0f);
  }
  __syncthreads();
  for (int i = tid; i < NCHN * NT; i += 512) {
    int c = i / NT, t = i - c * NT;
    float2 m = mxs[((size_t)(b * NCHN + c) * NFREQ + f) * NT + t];
    float w = Wsh[t];
    MWsh[c][t] = make_float2(w * m.x, -w * m.y);
  }
  __syncthreads();

  const float invT = 1.0f / (float)NT;
  const int TQ[5] = {0, 126, 252, 378, NT};
  int wave = tid >> 6;
  int lane = tid & 63;
  bool isR = (wave < 4) && (lane < NR_TILES);
  bool isP = (wave >= 4) && (lane < NP_THREADS);

  float x00 = 0.f, y00 = 0.f, x01 = 0.f, y01 = 0.f;
  float x10 = 0.f, y10 = 0.f, x11 = 0.f, y11 = 0.f;
  int pb = 0, qb = 0, pc = 0;

  if (isR) {
    int seg = wave;
    int tlo = TQ[seg], thi = TQ[seg + 1];
    int I = (int)((sqrtf(8.0f * (float)lane + 1.0f) - 1.0f) * 0.5f);
    while ((I + 1) * (I + 2) / 2 <= lane) ++I;
    while (I * (I + 1) / 2 > lane) --I;
    int J = lane - I * (I + 1) / 2;
    pb = 2 * I; qb = 2 * J;
    float2 a0 = Ypad[pb + tlo], a1 = Ypad[pb + tlo + 1];
    float2 b0 = Ypad[qb + tlo], b1 = Ypad[qb + tlo + 1];
    int t = tlo;
    for (; t + 1 < thi; t += 2) {
      float2 a2 = Ypad[pb + 2 + t], a3 = Ypad[pb + 3 + t];  // one b128 (aligned)
      float2 b2 = Ypad[qb + 2 + t], b3 = Ypad[qb + 3 + t];
      float w0 = Wsh[t], w1 = Wsh[t + 1];
      float wax0 = w0 * a0.x, way0 = w0 * a0.y;
      float wax1 = w0 * a1.x, way1 = w0 * a1.y;
      x00 = fmaf(wax0, b0.x, fmaf(way0, b0.y, x00));
      y00 = fmaf(way0, b0.x, fmaf(-wax0, b0.y, y00));
      x01 = fmaf(wax0, b1.x, fmaf(way0, b1.y, x01));
      y01 = fmaf(way0, b1.x, fmaf(-wax0, b1.y, y01));
      x10 = fmaf(wax1, b0.x, fmaf(way1, b0.y, x10));
      y10 = fmaf(way1, b0.x, fmaf(-wax1, b0.y, y10));
      x11 = fmaf(wax1, b1.x, fmaf(way1, b1.y, x11));
      y11 = fmaf(way1, b1.x, fmaf(-wax1, b1.y, y11));
      float vax0 = w1 * a1.x, vay0 = w1 * a1.y;
      float vax1 = w1 * a2.x, vay1 = w1 * a2.y;
      x00 = fmaf(vax0, b1.x, fmaf(vay0, b1.y, x00));
      y00 = fmaf(vay0, b1.x, fmaf(-vax0, b1.y, y00));
      x01 = fmaf(vax0, b2.x, fmaf(vay0, b2.y, x01));
      y01 = fmaf(vay0, b2.x, fmaf(-vax0, b2.y, y01));
      x10 = fmaf(vax1, b1.x, fmaf(vay1, b1.y, x10));
      y10 = fmaf(vay1, b1.x, fmaf(-vax1, b1.y, y10));
      x11 = fmaf(vax1, b2.x, fmaf(vay1, b2.y, x11));
      y11 = fmaf(vay1, b2.x, fmaf(-vax1, b2.y, y11));
      a0 = a2; a1 = a3; b0 = b2; b1 = b3;
    }
    if (t < thi) {  // odd epilogue (seg 3)
      float w0 = Wsh[t];
      float wax0 = w0 * a0.x, way0 = w0 * a0.y;
      float wax1 = w0 * a1.x, way1 = w0 * a1.y;
      x00 = fmaf(wax0, b0.x, fmaf(way0, b0.y, x00));
      y00 = fmaf(way0, b0.x, fmaf(-wax0, b0.y, y00));
      x01 = fmaf(wax0, b1.x, fmaf(way0, b1.y, x01));
      y01 = fmaf(way0, b1.x, fmaf(-wax0, b1.y, y01));
      x10 = fmaf(wax1, b0.x, fmaf(way1, b0.y, x10));
      y10 = fmaf(way1, b0.x, fmaf(-wax1, b0.y, y10));
      x11 = fmaf(wax1, b1.x, fmaf(way1, b1.y, x11));
      y11 = fmaf(way1, b1.x, fmaf(-wax1, b1.y, y11));
    }
  } else if (isP) {
    int seg = wave - 4;
    int tlo = TQ[seg], thi = TQ[seg + 1];
    int ih = lane / NCHN;
    pc = lane - ih * NCHN;
    pb = 2 * ih;
    float2 a0 = Ypad[pb + tlo], a1 = Ypad[pb + tlo + 1];
    const float2* MW = &MWsh[pc][0];
    int t = tlo;
    for (; t + 1 < thi; t += 2) {
      float2 a2 = Ypad[pb + 2 + t], a3 = Ypad[pb + 3 + t];
      float2 m0 = MW[t], m1 = MW[t + 1];
      x00 += a0.x * m0.x - a0.y * m0.y;
      y00 += a0.x * m0.y + a0.y * m0.x;
      x10 += a1.x * m0.x - a1.y * m0.y;
      y10 += a1.x * m0.y + a1.y * m0.x;
      x00 += a1.x * m1.x - a1.y * m1.y;
      y00 += a1.x * m1.y + a1.y * m1.x;
      x10 += a2.x * m1.x - a2.y * m1.y;
      y10 += a2.x * m1.y + a2.y * m1.x;
      a0 = a2; a1 = a3;
    }
    if (t < thi) {
      float2 m0 = MW[t];
      x00 += a0.x * m0.x - a0.y * m0.y;
      y00 += a0.x * m0.y + a0.y * m0.x;
      x10 += a1.x * m0.x - a1.y * m0.y;
      y10 += a1.x * m0.y + a1.y * m0.x;
    }
  }
  __syncthreads();    // all loop reads (Ypad, MWsh, Wsh) complete

  float* scratch = (float*)MWsh;  // dead now; need 2040 floats of 24240
  if (isR && wave >= 1) {
    float* d = scratch + ((wave - 1) * NR_TILES + lane) * 8;
    d[0] = x00; d[1] = y00; d[2] = x01; d[3] = y01;
    d[4] = x10; d[5] = y10; d[6] = x11; d[7] = y11;
  }
  if (isP && wave >= 5) {
    float* d = scratch + 3 * NR_TILES * 8 + ((wave - 5) * NP_THREADS + lane) * 4;
    d[0] = x00; d[1] = y00; d[2] = x10; d[3] = y10;
  }
  __syncthreads();

  if (isR && wave == 0) {
#pragma unroll
    for (int sgi = 0; sgi < 3; ++sgi) {
      const float* d = scratch + (sgi * NR_TILES + lane) * 8;
      x00 += d[0]; y00 += d[1]; x01 += d[2]; y01 += d[3];
      x10 += d[4]; y10 += d[5]; x11 += d[6]; y11 += d[7];
    }
    float2* Rg = R + (size_t)g * TAPS * TAPS;
#define STORE_R(p_, q_, xx, yy)                                       \
    if ((p_) >= (q_)) {                                                \
      float rx = (xx) * invT, ry = (yy) * invT;                        \
      Rg[(p_) * TAPS + (q_)] = make_float2(rx, ry);                    \
      if ((p_) != (q_)) Rg[(q_) * TAPS + (p_)] = make_float2(rx, -ry); \
    }
    STORE_R(pb, qb, x00, y00)
    STORE_R(pb, qb + 1, x01, y01)
    STORE_R(pb + 1, qb, x10, y10)
    STORE_R(pb + 1, qb + 1, x11, y11)
#undef STORE_R
  }
  if (isP && wave == 4) {
#pragma unroll
    for (int sgi = 0; sgi < 3; ++sgi) {
      const float* d = scratch + 3 * NR_TILES * 8 + (sgi * NP_THREADS + lane) * 4;
      x00 += d[0]; y00 += d[1]; x10 += d[2]; y10 += d[3];
    }
    float2* Pg = P + (size_t)g * TAPS * NCHN;
    Pg[pb * NCHN + pc] = make_float2(x00 * invT, y00 * invT);
    Pg[(pb + 1) * NCHN + pc] = make_float2(x10 * invT, y10 * invT);
  }
}

// ---------------- Cholesky solve (complex128; R+lambda*I is HPD) ----------------
// A = L L^H, lower triangle; forward/backward per-column. No pivoting needed.
__global__ void solve_kernel(const float2* __restrict__ R, const float2* __restrict__ P,
                             float* __restrict__ gout, float2* __restrict__ gct) {
  __shared__ double2 A[TAPS][TAPS];
  __shared__ double2 Bm[TAPS][NCHN];
  int g = blockIdx.x;
  int tid = threadIdx.x;
  int s = g & 1;
  int bf = g >> 1;
  int f = bf % NFREQ;
  int b = bf / NFREQ;
  int bs = b * NSPK + s;

  for (int i = tid; i < TAPS * TAPS; i += 64) {
    float2 r = R[(size_t)g * TAPS * TAPS + i];
    A[i / TAPS][i % TAPS] = make_double2((double)r.x, (double)r.y);
  }
  for (int i = tid; i < TAPS * NCHN; i += 64) {
    float2 p = P[(size_t)g * TAPS * NCHN + i];
    Bm[i / NCHN][i % NCHN] = make_double2((double)p.x, (double)p.y);
  }
  __syncthreads();
  if (tid < TAPS) A[tid][tid].x += LAMBDA_REG;
  __syncthreads();

  for (int k = 0; k < TAPS; ++k) {
    if (tid == 0) A[k][k].x = sqrt(A[k][k].x);
    __syncthreads();
    double d = A[k][k].x;
    if (tid > k && tid < TAPS) {
      A[tid][k].x /= d;
      A[tid][k].y /= d;
    }
    __syncthreads();
    int w = TAPS - 1 - k;
    for (int idx = tid; idx < w * w; idx += 64) {
      int i = k + 1 + idx / w;
      int j = k + 1 + idx % w;
      if (i >= j) {  // lower triangle only
        double2 a = A[i][k], bb = A[j][k];  // A[i][j] -= a * conj(bb)
        A[i][j].x -= a.x * bb.x + a.y * bb.y;
        A[i][j].y -= a.y * bb.x - a.x * bb.y;
      }
    }
    __syncthreads();
  }

  // 6 RHS: thread c handles column c
  if (tid < NCHN) {
    int c = tid;
    for (int k = 0; k < TAPS; ++k) {  // forward L y = B
      double sx = Bm[k][c].x, sy = Bm[k][c].y;
      for (int j = 0; j < k; ++j) {
        double2 l = A[k][j], y = Bm[j][c];
        sx -= l.x * y.x - l.y * y.y;
        sy -= l.x * y.y + l.y * y.x;
      }
      double d = A[k][k].x;
      Bm[k][c] = make_double2(sx / d, sy / d);
    }
    for (int k = TAPS - 1; k >= 0; --k) {  // backward L^H x = y
      double sx = Bm[k][c].x, sy = Bm[k][c].y;
      for (int j = k + 1; j < TAPS; ++j) {
        double2 l = A[j][k], xv = Bm[j][c];  // conj(l)*x
        sx -= l.x * xv.x + l.y * xv.y;
        sy -= l.x * xv.y - l.y * xv.x;
      }
      double d = A[k][k].x;
      Bm[k][c] = make_double2(sx / d, sy / d);
    }
  }
  __syncthreads();

  for (int i = tid; i < TAPS * NCHN; i += 64) {
    int p = i / NCHN, c = i - p * NCHN;
    double2 gv = Bm[p][c];
    float gx = (float)gv.x, gy = (float)(-gv.y);  // conj(G)
    gout[(size_t)g * TAPS * NCHN + i] = gx;       // float32, real part only
    gct[(((size_t)bs * TAPS + p) * NCHN + c) * NFREQ + f] = make_float2(gx, gy);
  }
}

// ---------------- ret + inverse FFT (quad-frame, XCD-swizzled) ----------------
__global__ void ret_ifft_kernel(const float2* __restrict__ spht, const float2* __restrict__ gct,
                                float* __restrict__ frames) {
  __shared__ float2 buf[4 * NFFT];
  constexpr int NBLK = NSIG * NCH4;
  int bid = blockIdx.x;
  int blk = (bid & 7) * (NBLK / 8) + (bid >> 3);  // XCD-aware swizzle
  int ch = blk % NCH4;
  int sc = blk / NCH4;
  int t0 = ch * 4;
  int nv = min(4, NT - t0);
  int c = sc % NCHN;
  int bs = sc / NCHN;
  int tid = threadIdx.x;

  const float2* gbase = gct + ((size_t)bs * TAPS * NCHN + c) * NFREQ;
  const float2* ysig = spht + (size_t)bs * NT * NFREQ;
  for (int f = tid; f < NFREQ; f += 256) {
    float sx0 = 0.f, sy0 = 0.f, sx1 = 0.f, sy1 = 0.f;
    float sx2 = 0.f, sy2 = 0.f, sx3 = 0.f, sy3 = 0.f;
    float2 g1p = make_float2(0.f, 0.f), g2p = make_float2(0.f, 0.f),
           g3p = make_float2(0.f, 0.f);
#pragma unroll
    for (int k = 0; k <= TAPS + 2; ++k) {  // frame j uses G[k-j]; ring holds zeros OOB
      int u = t0 - (TAPS - 1) + k;
      float2 y = (u >= 0 && u < NT) ? ysig[(size_t)u * NFREQ + f] : make_float2(0.f, 0.f);
      float2 gc = (k < TAPS) ? gbase[(size_t)k * NCHN * NFREQ + f] : make_float2(0.f, 0.f);
      sx0 += y.x * gc.x - y.y * gc.y;   sy0 += y.x * gc.y + y.y * gc.x;
      sx1 += y.x * g1p.x - y.y * g1p.y; sy1 += y.x * g1p.y + y.y * g1p.x;
      sx2 += y.x * g2p.x - y.y * g2p.y; sy2 += y.x * g2p.y + y.y * g2p.x;
      sx3 += y.x * g3p.x - y.y * g3p.y; sy3 += y.x * g3p.y + y.y * g3p.x;
      g3p = g2p; g2p = g1p; g1p = gc;
    }
    int r = rev9(f);
    buf[r] = make_float2(sx0, sy0);
    buf[NFFT + r] = make_float2(sx1, sy1);
    buf[2 * NFFT + r] = make_float2(sx2, sy2);
    buf[3 * NFFT + r] = make_float2(sx3, sy3);
    if (f > 0 && f < NFFT / 2) {
      int r2 = rev9(NFFT - f);
      buf[r2] = make_float2(sx0, -sy0);
      buf[NFFT + r2] = make_float2(sx1, -sy1);
      buf[2 * NFFT + r2] = make_float2(sx2, -sy2);
      buf[3 * NFFT + r2] = make_float2(sx3, -sy3);
    }
  }
  __syncthreads();
  fft512_quad(buf, tid, +1.0f);

  float* frow = frames + ((size_t)sc * NT + t0) * NFFT;
  for (int n = tid; n < NFFT; n += 256) {
    float w = __sinf(PI_F * (float)n / (float)NFFT);
#pragma unroll
    for (int j = 0; j < 4; ++j)
      if (j < nv) frow[(size_t)j * NFFT + n] = buf[j * NFFT + n].x * (1.0f / (float)NFFT) * w;
  }
}

// ---------------- overlap-add + env normalize + crop (float32 out) ----------------
__global__ void ola_kernel(const float* __restrict__ frames, float* __restrict__ out) {
  int i = blockIdx.x * 256 + threadIdx.x;
  if (i >= NSIG * LSIG) return;
  int sig = i / LSIG;
  int l = i - sig * LSIG;
  int lp = l + NFFT / 2;
  int j0 = max(0, (lp - (NFFT - HOPSZ)) / HOPSZ);
  int j1 = min(NT - 1, lp / HOPSZ);
  float acc = 0.0f;
  for (int j = j0; j <= j1; ++j) {
    int n = lp - j * HOPSZ;
    acc += frames[((size_t)sig * NT + j) * NFFT + n];
  }
  float env;
  if (j1 - j0 == 3) {
    env = 2.0f;  // sum sin^2(theta + k*pi/4), k=0..3 == 2 exactly
  } else {
    env = 0.0f;
    for (int j = j0; j <= j1; ++j) {
      int n = lp - j * HOPSZ;
      float w = __sinf(PI_F * (float)n / (float)NFFT);
      env += w * w;
    }
    if (env <= 1e-11f) env = 1.0f;
  }
  out[(size_t)G_ELEMS + i] = acc / env;
}

}  // namespace

extern "C" void kernel_launch(void* const* d_in, const int* in_sizes, int n_in,
                              void* d_out, int out_size, void* d_ws, size_t ws_size,
                              hipStream_t stream) {
  const float* ref = (const float*)d_in[0];
  const float* mix = (const float*)d_in[1];
  if (n_in >= 2 && in_sizes[0] > in_sizes[1]) {
    const float* tmp = ref; ref = mix; mix = tmp;
  }
  char* ws = (char*)d_ws;

  float2*  sph   = (float2*)(ws + SPH_B);
  float2*  spht  = (float2*)(ws + SPHT_B);
  float2*  mxs   = (float2*)(ws + MXS_B);
  float*   power = (float*)(ws + POW_B);
  float*   mx    = (float*)(ws + MX_B);
  float2*  R     = (float2*)(ws + R_B);
  float2*  P     = (float2*)(ws + P_B);
  float2*  gct   = (float2*)(ws + GCT_B);
  float*   frames= (float*)(ws + FRM_B);
  float*   out   = (float*)d_out;

  stft_kernel<<<dim3((NB * NSPK + NB * NCHN) * NCH4), dim3(256), 0, stream>>>(ref, mix, sph, spht, mxs);
  power_kernel<<<dim3((NB * NFREQ * NT + 255) / 256), dim3(256), 0, stream>>>(mxs, power);
  max_kernel<<<dim3(NB), dim3(256), 0, stream>>>(power, mx);
  rp_kernel<<<dim3(NG), dim3(512), 0, stream>>>(sph, mxs, power, mx, R, P);
  solve_kernel<<<dim3(NG), dim3(64), 0, stream>>>(R, P, out, gct);
  ret_ifft_kernel<<<dim3(NSIG * NCH4), dim3(256), 0, stream>>>(spht, gct, frames);
  ola_kernel<<<dim3((NSIG * LSIG + 255) / 256), dim3(256), 0, stream>>>(frames, out);
}